// Round 12
// baseline (427.241 us; speedup 1.0000x reference)
//
#include <hip/hip_runtime.h>

// ---------------- problem constants ----------------
#define Nq   4096
#define DHq  64
#define Mq   256
#define BHq  32

using bf16 = __bf16;
using bf16x8 = __bf16 __attribute__((ext_vector_type(8)));
using bf16x4 = __bf16 __attribute__((ext_vector_type(4)));
using f32x4 = float __attribute__((ext_vector_type(4)));

__device__ __forceinline__ f32x4 mfma16(bf16x8 a, bf16x8 b, f32x4 c) {
  return __builtin_amdgcn_mfma_f32_16x16x32_bf16(a, b, c, 0, 0, 0);
}
__device__ __forceinline__ unsigned short f2bu(float f) {
  bf16 b = (bf16)f;
  return __builtin_bit_cast(unsigned short, b);
}
__device__ __forceinline__ void split_store(bf16* h, bf16* l, long idx, float v) {
  bf16 hi = (bf16)v;
  h[idx] = hi;
  l[idx] = (bf16)(v - (float)hi);
}

// async global->LDS, 16B per lane; LDS dest = wave-uniform base + lane*16
typedef const __attribute__((address_space(1))) void* gas_t;
typedef __attribute__((address_space(3))) void* las_t;
__device__ __forceinline__ void glds16(const bf16* g, bf16* l) {
  __builtin_amdgcn_global_load_lds((gas_t)g, (las_t)l, 16, 0, 0);
}

// Stage a ROWS x 32 bf16 tile into LDS, row stride 40 bf16 (80 B).
// SRC: 0 = bf16 row-major, 1 = f32 row-major
template<int ROWS, int SRC>
__device__ __forceinline__ void stageA(const void* src, long ld, long row0, int k0,
                                       bf16* dst, int t) {
#pragma unroll
  for (int c = 0; c < ROWS / 64; ++c) {
    int idx = t + 256 * c;
    int r = idx >> 2;
    int kc = (idx & 3) << 3;
    bf16x8 val;
    if constexpr (SRC == 0) {
      val = *(const bf16x8*)((const bf16*)src + (row0 + r) * ld + k0 + kc);
    } else {
      const float* s = (const float*)src + (row0 + r) * ld + k0 + kc;
      float4 a = *(const float4*)s;
      float4 b = *(const float4*)(s + 4);
      val[0]=(bf16)a.x; val[1]=(bf16)a.y; val[2]=(bf16)a.z; val[3]=(bf16)a.w;
      val[4]=(bf16)b.x; val[5]=(bf16)b.y; val[6]=(bf16)b.z; val[7]=(bf16)b.w;
    }
    *(bf16x8*)(dst + r * 40 + kc) = val;
  }
}

// Stage 32 x COLS tile of row-major [K][N] B into word-LDS [COLS][20 words].
template<int COLS, bool F32>
__device__ __forceinline__ void stageBN(const void* src, long ld, long n0, int k0,
                                        unsigned int* dst, int t) {
  int kp = t >> 4;
  int nb = (t & 15) << 2;
#pragma unroll
  for (int g = 0; g < COLS / 64; ++g) {
    int n = nb + (g << 6);
    unsigned int w0, w1, w2, w3;
    if constexpr (F32) {
      const float* s0 = (const float*)src + (long)(k0 + 2 * kp) * ld + n0 + n;
      const float* s1 = s0 + ld;
      float4 a = *(const float4*)s0;
      float4 b = *(const float4*)s1;
      w0 = f2bu(a.x) | ((unsigned)f2bu(b.x) << 16);
      w1 = f2bu(a.y) | ((unsigned)f2bu(b.y) << 16);
      w2 = f2bu(a.z) | ((unsigned)f2bu(b.z) << 16);
      w3 = f2bu(a.w) | ((unsigned)f2bu(b.w) << 16);
    } else {
      const unsigned short* s0 = (const unsigned short*)src + (long)(k0 + 2 * kp) * ld + n0 + n;
      const unsigned short* s1 = s0 + ld;
      ushort4 a = *(const ushort4*)s0;
      ushort4 b = *(const ushort4*)s1;
      w0 = a.x | ((unsigned)b.x << 16);
      w1 = a.y | ((unsigned)b.y << 16);
      w2 = a.z | ((unsigned)b.z << 16);
      w3 = a.w | ((unsigned)b.w << 16);
    }
    dst[(n + 0) * 20 + kp] = w0;
    dst[(n + 1) * 20 + kp] = w1;
    dst[(n + 2) * 20 + kp] = w2;
    dst[(n + 3) * 20 + kp] = w3;
  }
}

#define EQKV 0
#define EA2 1
#define EWT 8
#define EBIAS 9

struct GP {
  const void* A; const void* Al;
  const void* B; const void* Bl;
  long ldA, ldB, sA, sB;
  int K;
  void* C0; void* C1; void* C2;
  long sC, ldC;
  const void* x0; const void* x1;
  const float* bias;
};

// ---------------- mgemm (kept for attn2 / Wt small gemms) ----------------
template<int BM, int BN, int WX, int ASRC, int BMODE, int SPLIT, int EPI, int SWZ>
__global__ __launch_bounds__(256, 2) void mgemm(GP p) {
  constexpr int WY = 4 / WX;
  constexpr int TM = BM / WY, TN = BN / WX;
  constexpr int IT = TM / 16, JT = TN / 16;
  constexpr int AB = (SPLIT ? 2 : 1) * BM * 80;
  constexpr int BB = (SPLIT ? 2 : 1) * BN * 80;
  __shared__ __align__(16) char Lbuf[AB + BB];
  bf16* AsL = (bf16*)Lbuf;
  unsigned int* BsL = (unsigned int*)(Lbuf + AB);
  int t = threadIdx.x;
  int wv = t >> 6, lane = t & 63;
  int wy = wv / WX, wx = wv % WX;
  int qd = lane >> 4, lm = lane & 15;
  long bz = blockIdx.z, m0 = (long)blockIdx.y * BM, n0 = (long)blockIdx.x * BN;

  const void* Ap = (const bf16*)p.A + bz * p.sA;
  const void* Alp = nullptr;
  if constexpr (SPLIT) Alp = (const bf16*)p.Al + bz * p.sA;
  const void* Bp = (const bf16*)p.B + bz * p.sB;
  const void* Blp = nullptr;
  if constexpr (SPLIT) Blp = (const bf16*)p.Bl + bz * p.sB;

  f32x4 acc[IT][JT];
#pragma unroll
  for (int i = 0; i < IT; ++i)
#pragma unroll
    for (int j = 0; j < JT; ++j) acc[i][j] = (f32x4)0.0f;

  for (int k0 = 0; k0 < p.K; k0 += 32) {
    stageA<BM, ASRC>(Ap, p.ldA, m0, k0, AsL, t);
    if constexpr (SPLIT) stageA<BM, 0>(Alp, p.ldA, m0, k0, AsL + BM * 40, t);
    if constexpr (BMODE == 0) {
      stageA<BN, 0>(Bp, p.ldB, n0, k0, (bf16*)BsL, t);
      if constexpr (SPLIT) stageA<BN, 0>(Blp, p.ldB, n0, k0, (bf16*)BsL + BN * 40, t);
    } else {
      stageBN<BN, false>(Bp, p.ldB, n0, k0, BsL, t);
      if constexpr (SPLIT) stageBN<BN, false>(Blp, p.ldB, n0, k0, BsL + BN * 20, t);
    }
    __syncthreads();
    bf16x8 af[IT], afl[IT];
#pragma unroll
    for (int i = 0; i < IT; ++i) {
      int m = wy * TM + i * 16 + lm;
      af[i] = *(const bf16x8*)(AsL + m * 40 + qd * 8);
      if constexpr (SPLIT) afl[i] = *(const bf16x8*)(AsL + BM * 40 + m * 40 + qd * 8);
    }
#pragma unroll
    for (int j = 0; j < JT; ++j) {
      int n = wx * TN + j * 16 + lm;
      bf16x8 bf, bfl;
      if constexpr (BMODE == 0) {
        bf = *(const bf16x8*)((const bf16*)BsL + n * 40 + qd * 8);
        if constexpr (SPLIT) bfl = *(const bf16x8*)((const bf16*)BsL + BN * 40 + n * 40 + qd * 8);
      } else {
        bf = *(const bf16x8*)((const bf16*)(BsL + n * 20 + qd * 4));
        if constexpr (SPLIT) bfl = *(const bf16x8*)((const bf16*)(BsL + BN * 20 + n * 20 + qd * 4));
      }
#pragma unroll
      for (int i = 0; i < IT; ++i) {
        acc[i][j] = mfma16(af[i], bf, acc[i][j]);
        if constexpr (SPLIT) {
          acc[i][j] = mfma16(af[i], bfl, acc[i][j]);
          acc[i][j] = mfma16(afl[i], bf, acc[i][j]);
        }
      }
    }
    __syncthreads();
  }

  if constexpr (EPI == EA2) {
#pragma unroll
    for (int r = 0; r < 4; ++r) {
      long row = m0 + wy * TM + qd * 4 + r;
      float e[JT];
      float s = 0.f;
#pragma unroll
      for (int j = 0; j < JT; ++j) { e[j] = __expf(acc[0][j][r]); s += e[j]; }
      s += __shfl_xor(s, 1); s += __shfl_xor(s, 2);
      s += __shfl_xor(s, 4); s += __shfl_xor(s, 8);
      float inv = 1.0f / s;
#pragma unroll
      for (int j = 0; j < JT; ++j) {
        long col = n0 + j * 16 + lm;
        split_store((bf16*)p.C0, (bf16*)p.C1, bz * p.sC + row * p.ldC + col, e[j] * inv);
      }
    }
  } else {
#pragma unroll
    for (int i = 0; i < IT; ++i)
#pragma unroll
      for (int j = 0; j < JT; ++j)
#pragma unroll
        for (int r = 0; r < 4; ++r) {
          long row = m0 + wy * TM + i * 16 + qd * 4 + r;
          long col = n0 + wx * TN + j * 16 + lm;
          float v = acc[i][j][r];
          if constexpr (EPI == EWT) {
            ((bf16*)p.C0)[bz * 16384 + col * 256 + row] = (bf16)v;
          }
        }
  }
}

// ---------------- glds-staged 128x128 gemm (QKV + out-proj, BK=64) ----------------
template<int ASRC, int EPI, int SWZ>
__global__ __launch_bounds__(256, 3) void ggemm(GP p) {
  __shared__ __align__(64) bf16 AsL[2][128 * 32];
  __shared__ __align__(64) bf16 BsL[2][128 * 32];
  int t = threadIdx.x, wv = t >> 6, lane = t & 63;
  int wy = wv >> 1, wx = wv & 1;
  int qd = lane >> 4, lm = lane & 15;
  long m0, n0;
  if constexpr (SWZ == 1) {
    int b = blockIdx.x, xcd = b & 7, s = b >> 3;
    m0 = (long)(xcd * 16 + s / 12) * 128; n0 = (long)(s % 12) * 128;
  } else {
    int b = blockIdx.x, xcd = b & 7, s = b >> 3;
    m0 = (long)(xcd * 16 + (s >> 2)) * 128; n0 = (long)(s & 3) * 128;
  }
  const bf16* A = (const bf16*)p.A;
  const bf16* B = (const bf16*)p.B;

  f32x4 acc[4][4];
#pragma unroll
  for (int i = 0; i < 4; ++i)
#pragma unroll
    for (int j = 0; j < 4; ++j) acc[i][j] = (f32x4)0.0f;

  int rsub = lane >> 2;           // 0..15 row within 16-row group
  int kc = (lane & 3) << 3;       // 0,8,16,24 bf16 col offset
  for (int k0 = 0; k0 < p.K; k0 += 64) {
#pragma unroll
    for (int half = 0; half < 2; ++half) {
      int kk = k0 + half * 32;
#pragma unroll
      for (int e = 0; e < 2; ++e) {
        int br = wv * 32 + e * 16;          // wave-uniform base row
        long rA = m0 + br + rsub;
        const bf16* gA;
        if constexpr (ASRC == 0) {
          gA = A + rA * p.ldA + kk + kc;
        } else {
          long bb = rA >> 12, ii = rA & 4095;
          int k = kk + kc;
          long h = k >> 6, d = k & 63;
          gA = A + (((bb * 8 + h) * 4096 + ii) * 64 + d);
        }
        glds16(gA, AsL[half] + br * 32);
        const bf16* gB = B + (n0 + br + rsub) * p.ldB + kk + kc;
        glds16(gB, BsL[half] + br * 32);
      }
    }
    __syncthreads();
#pragma unroll
    for (int half = 0; half < 2; ++half) {
      bf16x8 af[4];
#pragma unroll
      for (int i = 0; i < 4; ++i)
        af[i] = *(const bf16x8*)(AsL[half] + (wy * 64 + i * 16 + lm) * 32 + qd * 8);
#pragma unroll
      for (int j = 0; j < 4; ++j) {
        bf16x8 bv = *(const bf16x8*)(BsL[half] + (wx * 64 + j * 16 + lm) * 32 + qd * 8);
#pragma unroll
        for (int i = 0; i < 4; ++i) acc[i][j] = mfma16(af[i], bv, acc[i][j]);
      }
    }
    __syncthreads();
  }

#pragma unroll
  for (int i = 0; i < 4; ++i)
#pragma unroll
    for (int j = 0; j < 4; ++j)
#pragma unroll
      for (int r = 0; r < 4; ++r) {
        long row = m0 + wy * 64 + i * 16 + qd * 4 + r;
        long col = n0 + wx * 64 + j * 16 + lm;
        float v = acc[i][j][r];
        if constexpr (EPI == EQKV) {
          int part = (int)(col >> 9);
          long h = (col >> 6) & 7, d = col & 63;
          long bb = row >> 12, ii = row & 4095;
          float scv = part == 0 ? 0.125f : 1.0f;
          bf16* dst = part == 0 ? (bf16*)p.C0 : (part == 1 ? (bf16*)p.C1 : (bf16*)p.C2);
          dst[((bb * 8 + h) * 4096 + ii) * 64 + d] = (bf16)(v * scv);
        } else {
          ((float*)p.C0)[row * 512 + col] = v + p.bias[col];
        }
      }
}

// ---------------- fused prep: x->bf16 cast + zeroing + weight transposes ------
// blocks 0..4095: x cast + workspace zero; blocks 4096..4351: wtrans (merged
// to save one launch; branch is block-uniform so the inner barrier is safe).
__global__ __launch_bounds__(256) void k_prep(const float* __restrict__ x,
                                              bf16* __restrict__ xb,
                                              float* a3vf, float* rs3, unsigned int* sc,
                                              const float* __restrict__ wq,
                                              const float* __restrict__ wo,
                                              bf16* __restrict__ wqt,
                                              bf16* __restrict__ wot) {
  __shared__ float T[64][65];
  int bid = blockIdx.x, t = threadIdx.x;
  if (bid < 4096) {
    long i = (long)bid * 256 + t;
    long e = i * 8;
    float4 a = *(const float4*)(x + e);
    float4 b = *(const float4*)(x + e + 4);
    bf16x8 v;
    v[0]=(bf16)a.x; v[1]=(bf16)a.y; v[2]=(bf16)a.z; v[3]=(bf16)a.w;
    v[4]=(bf16)b.x; v[5]=(bf16)b.y; v[6]=(bf16)b.z; v[7]=(bf16)b.w;
    *(bf16x8*)(xb + e) = v;
    if (i < 524288) a3vf[i] = 0.f;
    if (i < 8192) rs3[i] = 0.f;
    if (i == 0) sc[0] = 0u;
  } else {
    int w = bid - 4096;           // 0..255
    int bx = w >> 3, ti = w & 7;
    const float* src; bf16* dst; int N, tj;
    if (bx < 24) { src = wq; dst = wqt; N = 1536; tj = bx; }
    else         { src = wo; dst = wot; N = 512;  tj = bx - 24; }
    int c = t & 63, r0 = t >> 6;
#pragma unroll
    for (int rr = 0; rr < 16; ++rr) {
      int r = r0 * 16 + rr;
      T[r][c] = src[(long)(ti * 64 + r) * N + tj * 64 + c];
    }
    __syncthreads();
#pragma unroll
    for (int rr = 0; rr < 16; ++rr) {
      int n = r0 * 16 + rr;
      dst[(long)(tj * 64 + n) * 512 + ti * 64 + c] = (bf16)T[c][n];
    }
  }
}

// ---------------- strip-resident Newton-Schulz (32-col strips, 256 blocks) ----
// 1024 threads/block (16 waves/CU); verified round 8.
#define SBW 132

__device__ __forceinline__ void stageBS32(const bf16* src, long n0, int k0,
                                          unsigned int* dst, int t) {
  int kp = t >> 3, nb = (t & 7) << 2;
  const unsigned short* s0 = (const unsigned short*)src + (long)(k0 + 2 * kp) * 256 + n0 + nb;
  const unsigned short* s1 = s0 + 256;
  ushort4 a = *(const ushort4*)s0;
  ushort4 b = *(const ushort4*)s1;
  int wb = (k0 >> 1) + kp;
  dst[(nb + 0) * SBW + wb] = a.x | ((unsigned)b.x << 16);
  dst[(nb + 1) * SBW + wb] = a.y | ((unsigned)b.y << 16);
  dst[(nb + 2) * SBW + wb] = a.z | ((unsigned)b.z << 16);
  dst[(nb + 3) * SBW + wb] = a.w | ((unsigned)b.w << 16);
}

// C rows [w*16, w*16+16) x 32 cols = A-rows(global) @ B_strip(LDS). 16 waves.
template<int SPLIT>
__device__ __forceinline__ void sgemm32(const bf16* Ah, const bf16* Al,
                                        const unsigned int* Bs, const unsigned int* Bsl,
                                        int w, int lane, f32x4 acc[2]) {
  int qd = lane >> 4, lm = lane & 15;
  acc[0] = (f32x4)0.0f;
  acc[1] = (f32x4)0.0f;
#pragma unroll 2
  for (int k0 = 0; k0 < 256; k0 += 32) {
    long m = w * 16 + lm;
    bf16x8 af = *(const bf16x8*)(Ah + m * 256 + k0 + qd * 8);
    bf16x8 afl;
    if constexpr (SPLIT) afl = *(const bf16x8*)(Al + m * 256 + k0 + qd * 8);
#pragma unroll
    for (int j = 0; j < 2; ++j) {
      bf16x8 bv = *(const bf16x8*)((const bf16*)(Bs + (j * 16 + lm) * SBW + (k0 >> 1) + qd * 4));
      acc[j] = mfma16(af, bv, acc[j]);
      if constexpr (SPLIT) {
        bf16x8 bl = *(const bf16x8*)((const bf16*)(Bsl + (j * 16 + lm) * SBW + (k0 >> 1) + qd * 4));
        acc[j] = mfma16(af, bl, acc[j]);
        acc[j] = mfma16(afl, bv, acc[j]);
      }
    }
  }
}

// pack 4 rows (R0..R0+3) of column col into transposed strip LDS (h, and l residual)
template<int HASL>
__device__ __forceinline__ void packStrip(unsigned int* Sh, unsigned int* Sl,
                                          int col, int R0, const float* v) {
  unsigned int* Wp = Sh + col * SBW + (R0 >> 1);
  Wp[0] = f2bu(v[0]) | ((unsigned)f2bu(v[1]) << 16);
  Wp[1] = f2bu(v[2]) | ((unsigned)f2bu(v[3]) << 16);
  if constexpr (HASL) {
    unsigned int* Wq = Sl + col * SBW + (R0 >> 1);
    Wq[0] = f2bu(v[0] - (float)(bf16)v[0]) | ((unsigned)f2bu(v[1] - (float)(bf16)v[1]) << 16);
    Wq[1] = f2bu(v[2] - (float)(bf16)v[2]) | ((unsigned)f2bu(v[3] - (float)(bf16)v[3]) << 16);
  }
}

// XCD-affine block -> (bh, strip) mapping
__device__ __forceinline__ void nsmap(int b, long& bh, long& js) {
  int xcd = b & 7, s = b >> 3;
  bh = xcd * 4 + (s >> 3);
  js = (long)(s & 7) * 32;
}

// y0 = A2 @ z0 (non-split inputs, split-stored output)
__global__ __launch_bounds__(1024) void k_nsy0(const bf16* __restrict__ A2h,
                                               const bf16* __restrict__ zh,
                                               bf16* __restrict__ yh, bf16* __restrict__ yl) {
  __shared__ __align__(16) unsigned int Bs[32 * SBW];
  int b = blockIdx.x, t = threadIdx.x;
  long bh, js;
  nsmap(b, bh, js);
  const bf16* Ah = A2h + bh * 65536;
  const bf16* Bz = zh + bh * 65536;
  if (t < 128) {
#pragma unroll
    for (int k0 = 0; k0 < 256; k0 += 32) stageBS32(Bz, js, k0, Bs, t);
  }
  __syncthreads();
  int w = t >> 6, lane = t & 63, qd = lane >> 4, lm = lane & 15;
  f32x4 acc[2];
  sgemm32<0>(Ah, Ah, Bs, Bs, w, lane, acc);
  bf16* yhb = yh + bh * 65536;
  bf16* ylb = yl + bh * 65536;
#pragma unroll
  for (int j = 0; j < 2; ++j)
#pragma unroll
    for (int r = 0; r < 4; ++r) {
      long row = w * 16 + qd * 4 + r;
      long col = js + j * 16 + lm;
      split_store(yhb, ylb, row * 256 + col, acc[j][r]);
    }
}

// One NS iteration for one 32-col strip (see round-8 comments).
template<int SPLIT, int YS>
__global__ __launch_bounds__(1024) void k_ns4(
    const bf16* __restrict__ A2h, const bf16* __restrict__ A2l,
    const bf16* __restrict__ yih, const bf16* __restrict__ yil,
    const bf16* __restrict__ zh_, const bf16* __restrict__ zl_,
    bf16* __restrict__ znh_, bf16* __restrict__ znl_,
    bf16* __restrict__ yoh_, bf16* __restrict__ yol_) {
  constexpr int P0 = SPLIT ? 2 : 1;
  constexpr int P1 = (SPLIT || YS == 1) ? 2 : 1;
  __shared__ __align__(16) unsigned int S0[P0][32 * SBW];
  __shared__ __align__(16) unsigned int S1[P1][32 * SBW];
  int b = blockIdx.x, t = threadIdx.x;
  long bh, js;
  nsmap(b, bh, js);
  const bf16* yH = yih + bh * 65536;
  const bf16* yL = yil + bh * 65536;
  const bf16* zH = zh_ + bh * 65536;
  const bf16* zL = zl_ + bh * 65536;
  const bf16* aH = A2h + bh * 65536;
  const bf16* aL = A2l + bh * 65536;
  unsigned int* S0l = S0[P0 - 1];
  unsigned int* S1l = S1[P1 - 1];
  if (t < 128) {
#pragma unroll
    for (int k0 = 0; k0 < 256; k0 += 32) {
      stageBS32(yH, js, k0, S0[0], t);
      if constexpr (SPLIT) stageBS32(yL, js, k0, S0l, t);
    }
  }
  __syncthreads();
  int w = t >> 6, lane = t & 63, qd = lane >> 4, lm = lane & 15;
  f32x4 acc[2];

  // gemm1: bb = 15I - 7y + y @ y_strip -> S1
  sgemm32<SPLIT>(yH, yL, S0[0], S0l, w, lane, acc);
#pragma unroll
  for (int j = 0; j < 2; ++j) {
    int R0 = w * 16 + qd * 4;
    int col = j * 16 + lm;
    float v[4];
#pragma unroll
    for (int r = 0; r < 4; ++r) {
      long row = R0 + r;
      long ix = row * 256 + js + col;
      float yv = (float)yH[ix] + (float)yL[ix];
      v[r] = ((row == js + col) ? 15.0f : 0.0f) - 7.0f * yv + acc[j][r];
    }
    packStrip<SPLIT>(S1[0], S1l, col, R0, v);
  }
  __syncthreads();

  // gemm2: cc = 13I - y @ bb_strip -> S0
  sgemm32<SPLIT>(yH, yL, S1[0], S1l, w, lane, acc);
#pragma unroll
  for (int j = 0; j < 2; ++j) {
    int R0 = w * 16 + qd * 4;
    int col = j * 16 + lm;
    float v[4];
#pragma unroll
    for (int r = 0; r < 4; ++r)
      v[r] = (((long)(R0 + r) == js + col) ? 13.0f : 0.0f) - acc[j][r];
    packStrip<SPLIT>(S0[0], S0l, col, R0, v);
  }
  __syncthreads();

  // gemm3: zn = 0.25 * z @ cc_strip -> global split [+ pack S1]
  sgemm32<SPLIT>(zH, zL, S0[0], S0l, w, lane, acc);
  bf16* zoh = znh_ + bh * 65536;
  bf16* zol = znl_ + bh * 65536;
#pragma unroll
  for (int j = 0; j < 2; ++j) {
    int R0 = w * 16 + qd * 4;
    int col = j * 16 + lm;
    float v[4];
#pragma unroll
    for (int r = 0; r < 4; ++r) {
      v[r] = 0.25f * acc[j][r];
      split_store(zoh, zol, (long)(R0 + r) * 256 + js + col, v[r]);
    }
    if constexpr (YS >= 0) packStrip<(YS == 1) ? 1 : 0>(S1[0], S1l, col, R0, v);
  }

  // gemm4: y' = A2 @ zn_strip -> global split
  if constexpr (YS >= 0) {
    __syncthreads();
    sgemm32<(YS == 1) ? 1 : 0>(aH, aL, S1[0], S1l, w, lane, acc);
    bf16* yoh = yoh_ + bh * 65536;
    bf16* yol = yol_ + bh * 65536;
#pragma unroll
    for (int j = 0; j < 2; ++j)
#pragma unroll
      for (int r = 0; r < 4; ++r) {
        long row = w * 16 + qd * 4 + r;
        long col = js + j * 16 + lm;
        split_store(yoh, yol, row * 256 + col, acc[j][r]);
      }
  }
}

// ---------------- flash a3v (kt=4, 512 blocks, KVBLK=128, T14) ----------------
// Verified round 11: 8 iterations x 3 barriers, 32 MFMA between barrier pairs.
__device__ __forceinline__ void loadKrow4(const bf16* ks_, int t, bf16x8 kr[4]) {
#pragma unroll
  for (int c = 0; c < 4; ++c) {
    int idx = t + 256 * c;
    int r = idx >> 3, dc = (idx & 7) * 8;
    kr[c] = *(const bf16x8*)(ks_ + r * 64 + dc);
  }
}
__device__ __forceinline__ void writeKrow4(bf16* kS, int t, const bf16x8 kr[4]) {
#pragma unroll
  for (int c = 0; c < 4; ++c) {
    int idx = t + 256 * c;
    int r = idx >> 3, dc = (idx & 7) * 8;
    *(bf16x8*)(kS + r * 72 + dc) = kr[c];
  }
}
__device__ __forceinline__ void loadVhalf(const bf16* vs_, int k0, int t,
                                          ushort4& a, ushort4& b) {
  int kp = t >> 4, nb = (t & 15) << 2;
  const unsigned short* s0 = (const unsigned short*)vs_ + (long)(k0 + 2 * kp) * 64 + nb;
  a = *(const ushort4*)s0;
  b = *(const ushort4*)(s0 + 64);
}
__device__ __forceinline__ void writeVhalf(unsigned int* dst, int t, ushort4 a, ushort4 b) {
  int kp = t >> 4, nb = (t & 15) << 2;
  dst[(nb + 0) * 20 + kp] = a.x | ((unsigned)b.x << 16);
  dst[(nb + 1) * 20 + kp] = a.y | ((unsigned)b.y << 16);
  dst[(nb + 2) * 20 + kp] = a.z | ((unsigned)b.z << 16);
  dst[(nb + 3) * 20 + kp] = a.w | ((unsigned)b.w << 16);
}

__global__ __launch_bounds__(256, 2) void k_a3v(const bf16* __restrict__ qlh,
                                                const bf16* __restrict__ kb,
                                                const bf16* __restrict__ vb,
                                                float* __restrict__ a3vf,
                                                float* __restrict__ rs3) {
  __shared__ __align__(16) char L[66048];
  bf16* qlS = (bf16*)L;                           // [64][72]
  bf16* kS  = (bf16*)(L + 9216);                  // [128][72]
  bf16* PA  = (bf16*)(L + 27648);                 // [64][136]
  unsigned int* vBb = (unsigned int*)(L + 45056); // 4 x [64][20] words
  float* rsL = (float*)(L + 65536);               // [64][2]
  int b = blockIdx.x, t = threadIdx.x;
  int xcd = b & 7, s = b >> 3;
  int strip = xcd * 16 + (s >> 2);
  int qt = s & 3;
  long bz = strip >> 2;
  int kt = strip & 3;
  int wv = t >> 6, lane = t & 63, qd = lane >> 4, lm = lane & 15;
  int wy = wv >> 1, wx = wv & 1;
  const bf16* qlp = qlh + bz * 16384 + qt * 64 * 64;
#pragma unroll
  for (int c = 0; c < 2; ++c) {
    int idx = t + 256 * c;
    int r = idx >> 3, dc = (idx & 7) * 8;
    *(bf16x8*)(qlS + r * 72 + dc) = *(const bf16x8*)(qlp + r * 64 + dc);
  }
  const bf16* kb_ = kb + bz * 262144 + (long)kt * 65536;
  const bf16* vb_ = vb + bz * 262144 + (long)kt * 65536;
  f32x4 accO[2][2];
  float rsum[2][4];
#pragma unroll
  for (int i = 0; i < 2; ++i) {
#pragma unroll
    for (int j = 0; j < 2; ++j) accO[i][j] = (f32x4)0.0f;
#pragma unroll
    for (int r = 0; r < 4; ++r) rsum[i][r] = 0.f;
  }
  // prefetch tt=0 into registers (128 K rows, 128 V rows)
  bf16x8 kr[4];
  ushort4 va[4], vbq[4];
  loadKrow4(kb_, t, kr);
#pragma unroll
  for (int q = 0; q < 4; ++q) loadVhalf(vb_, q * 32, t, va[q], vbq[q]);
  for (int tt = 0; tt < 8; ++tt) {
    __syncthreads();
    writeKrow4(kS, t, kr);
#pragma unroll
    for (int q = 0; q < 4; ++q) writeVhalf(vBb + q * 1280, t, va[q], vbq[q]);
    __syncthreads();
    if (tt < 7) {   // issue next tile's loads; they complete under QK/SM/PV
      const bf16* ks2 = kb_ + (tt + 1) * 8192;
      const bf16* vs2 = vb_ + (tt + 1) * 8192;
      loadKrow4(ks2, t, kr);
#pragma unroll
      for (int q = 0; q < 4; ++q) loadVhalf(vs2, q * 32, t, va[q], vbq[q]);
    }
    f32x4 s2[2][4];
#pragma unroll
    for (int i = 0; i < 2; ++i)
#pragma unroll
      for (int j = 0; j < 4; ++j) s2[i][j] = (f32x4)0.0f;
#pragma unroll
    for (int ks = 0; ks < 2; ++ks) {
      bf16x8 af[2];
#pragma unroll
      for (int i = 0; i < 2; ++i)
        af[i] = *(const bf16x8*)(qlS + (wy * 32 + i * 16 + lm) * 72 + ks * 32 + qd * 8);
#pragma unroll
      for (int j = 0; j < 4; ++j) {
        bf16x8 bfv = *(const bf16x8*)(kS + (wx * 64 + j * 16 + lm) * 72 + ks * 32 + qd * 8);
#pragma unroll
        for (int i = 0; i < 2; ++i) s2[i][j] = mfma16(af[i], bfv, s2[i][j]);
      }
    }
#pragma unroll
    for (int i = 0; i < 2; ++i)
#pragma unroll
      for (int r = 0; r < 4; ++r) {
        int row = wy * 32 + i * 16 + qd * 4 + r;
        float cs = 0.f;
#pragma unroll
        for (int j = 0; j < 4; ++j) {
          float e = __expf(s2[i][j][r]);
          PA[row * 136 + wx * 64 + j * 16 + lm] = (bf16)e;
          cs += e;
        }
        cs += __shfl_xor(cs, 1); cs += __shfl_xor(cs, 2);
        cs += __shfl_xor(cs, 4); cs += __shfl_xor(cs, 8);
        rsum[i][r] += cs;
      }
    __syncthreads();
#pragma unroll
    for (int ks = 0; ks < 4; ++ks) {
      const unsigned int* vB = vBb + ks * 1280;
      bf16x8 af[2];
#pragma unroll
      for (int i = 0; i < 2; ++i)
        af[i] = *(const bf16x8*)(PA + (wy * 32 + i * 16 + lm) * 136 + ks * 32 + qd * 8);
#pragma unroll
      for (int j = 0; j < 2; ++j) {
        bf16x8 bfv = *(const bf16x8*)((const bf16*)(vB + (wx * 32 + j * 16 + lm) * 20) + qd * 8);
#pragma unroll
        for (int i = 0; i < 2; ++i) accO[i][j] = mfma16(af[i], bfv, accO[i][j]);
      }
    }
  }
  if (lm == 0) {
#pragma unroll
    for (int i = 0; i < 2; ++i)
#pragma unroll
      for (int r = 0; r < 4; ++r)
        rsL[(wy * 32 + i * 16 + qd * 4 + r) * 2 + wx] = rsum[i][r];
  }
  __syncthreads();
  if (t < 64) atomicAdd(&rs3[bz * 256 + qt * 64 + t], rsL[t * 2] + rsL[t * 2 + 1]);
#pragma unroll
  for (int i = 0; i < 2; ++i)
#pragma unroll
    for (int j = 0; j < 2; ++j)
#pragma unroll
      for (int r = 0; r < 4; ++r) {
        long row = bz * 256 + qt * 64 + wy * 32 + i * 16 + qd * 4 + r;
        long col = wx * 32 + j * 16 + lm;
        atomicAdd(&a3vf[row * 64 + col], accO[i][j][r]);
      }
}

__global__ void k_a3vnorm(const float* __restrict__ a3vf, const float* __restrict__ rs3,
                          bf16* __restrict__ a3vh, bf16* __restrict__ a3vl) {
  long e0 = ((long)blockIdx.x * 256 + threadIdx.x) * 4;
  float4 vv = *(const float4*)&a3vf[e0];
  float inv = 1.0f / rs3[e0 >> 6];
  split_store(a3vh, a3vl, e0 + 0, vv.x * inv);
  split_store(a3vh, a3vl, e0 + 1, vv.y * inv);
  split_store(a3vh, a3vl, e0 + 2, vv.z * inv);
  split_store(a3vh, a3vl, e0 + 3, vv.w * inv);
}

// ---------------- small kernels ----------------
__global__ void k_landmarks(const bf16* q, const bf16* k, bf16* qlh, bf16* qll,
                            bf16* klh, bf16* kll) {
  int bm = blockIdx.x;
  int bh = bm >> 8, mi = bm & 255;
  int d = threadIdx.x;
  const bf16* qp = q + ((long)bh * 4096 + mi * 16) * 64 + d;
  const bf16* kp = k + ((long)bh * 4096 + mi * 16) * 64 + d;
  float sq = 0.f, sk = 0.f;
#pragma unroll
  for (int tt = 0; tt < 16; ++tt) { sq += (float)qp[tt * 64]; sk += (float)kp[tt * 64]; }
  sq *= 0.0625f; sk *= 0.0625f;
  long o = (long)bh * 16384 + mi * 64 + d;
  split_store(qlh, qll, o, sq);
  split_store(klh, kll, o, sk);
}

__global__ __launch_bounds__(256) void k_colsum(const bf16* A2h, const bf16* A2l,
                                                unsigned int* sc) {
  int bh = blockIdx.x, j = threadIdx.x;
  const bf16* ph = A2h + (long)bh * 65536 + j;
  const bf16* pl = A2l + (long)bh * 65536 + j;
  float s = 0.f;
  for (int i = 0; i < 256; ++i) s += (float)ph[i * 256] + (float)pl[i * 256];
  __shared__ float red[256];
  red[j] = s; __syncthreads();
  for (int o = 128; o > 0; o >>= 1) {
    if (j < o) red[j] = fmaxf(red[j], red[j + o]);
    __syncthreads();
  }
  if (j == 0) atomicMax(sc, __float_as_uint(red[0]));
}

__global__ __launch_bounds__(256) void k_zinit(const bf16* A2h, const bf16* A2l,
                                               const unsigned int* sc, bf16* zh, bf16* zl) {
  __shared__ float T[64][65];
  int bh = blockIdx.z, ti = blockIdx.y, tj = blockIdx.x;
  int t = threadIdx.x;
  int c = t & 63, r0 = t >> 6;
  long base = (long)bh * 65536;
  float inv = 1.0f / __uint_as_float(sc[0]);
#pragma unroll
  for (int rr = 0; rr < 16; ++rr) {
    int r = r0 * 16 + rr;
    long idx = base + (long)(ti * 64 + r) * 256 + tj * 64 + c;
    T[r][c] = (float)A2h[idx] + (float)A2l[idx];
  }
  __syncthreads();
#pragma unroll
  for (int rr = 0; rr < 16; ++rr) {
    int jl = r0 * 16 + rr;
    float v = T[c][jl] * inv;
    long o = base + (long)(tj * 64 + jl) * 256 + ti * 64 + c;
    split_store(zh, zl, o, v);
  }
}

// fused: oh = softmax(q @ kl^T) @ W  (bf16 out), Wt [bh][64][256]
// T14: all of Wt prefetched into registers at entry (returns under stage-1 +
// softmax), written once to resident LDS [2][64][136]; stage-2 runs all 32
// MFMA behind a single barrier (was 8 iters x 2 barriers with 4 MFMA each).
__global__ __launch_bounds__(256, 2) void k_attn1w(const bf16* qb, const bf16* klb,
                                                   const bf16* Wt, bf16* oh) {
  __shared__ __align__(16) char L[68608];
  bf16* Aq = (bf16*)L;             // [64][40]
  bf16* Bkl = (bf16*)(L + 5120);   // [256][40]
  bf16* Pl = (bf16*)L;             // [64][264] (reuse after stage-1)
  bf16* Bw2 = (bf16*)(L + 33792);  // [2][64][136]
  int t = threadIdx.x, wv = t >> 6, lane = t & 63;
  int qd = lane >> 4, lm = lane & 15;
  long bz = blockIdx.z;
  long m0 = (long)blockIdx.x * 64;
  const bf16* qA = qb + bz * (4096L * 64);
  const bf16* klA = klb + bz * (256L * 64);
  const bf16* WtA = Wt + bz * 16384;

  // T14: issue all Wt loads now; they complete under stage-1 + softmax
  bf16x8 wreg[8];
#pragma unroll
  for (int c = 0; c < 8; ++c) {
    int idx = t + 256 * c;
    int r = idx >> 5, kc = (idx & 31) * 8;
    wreg[c] = *(const bf16x8*)(WtA + r * 256 + kc);
  }

  f32x4 a1[16];
#pragma unroll
  for (int j = 0; j < 16; ++j) a1[j] = (f32x4)0.0f;
  for (int k0 = 0; k0 < 64; k0 += 32) {
    stageA<64, 0>(qA, 64, m0, k0, Aq, t);
    stageA<256, 0>(klA, 64, 0, k0, Bkl, t);
    __syncthreads();
    bf16x8 af = *(const bf16x8*)(Aq + (wv * 16 + lm) * 40 + qd * 8);
#pragma unroll
    for (int j = 0; j < 16; ++j) {
      bf16x8 bf = *(const bf16x8*)(Bkl + (j * 16 + lm) * 40 + qd * 8);
      a1[j] = mfma16(af, bf, a1[j]);
    }
    __syncthreads();
  }
  float rs[4];
#pragma unroll
  for (int r = 0; r < 4; ++r) {
    int rowl = wv * 16 + qd * 4 + r;
    float ev[16];
    float s = 0.f;
#pragma unroll
    for (int j = 0; j < 16; ++j) { ev[j] = __expf(a1[j][r]); s += ev[j]; }
    s += __shfl_xor(s, 1); s += __shfl_xor(s, 2);
    s += __shfl_xor(s, 4); s += __shfl_xor(s, 8);
    rs[r] = s;
#pragma unroll
    for (int j = 0; j < 16; ++j) {
      float other = __shfl_xor(ev[j], 1);
      if ((lm & 1) == 0) {
        unsigned int w = f2bu(ev[j]) | ((unsigned)f2bu(other) << 16);
        *(unsigned int*)(Pl + rowl * 264 + j * 16 + lm) = w;
      }
    }
  }
  // write Wt registers to resident LDS (split into two 128-k chunks)
#pragma unroll
  for (int c = 0; c < 8; ++c) {
    int idx = t + 256 * c;
    int r = idx >> 5, kc = (idx & 31) * 8;
    int ch = kc >> 7, kk = kc & 127;
    *(bf16x8*)(Bw2 + ch * 8704 + r * 136 + kk) = wreg[c];
  }
  __syncthreads();
  f32x4 a2[4];
#pragma unroll
  for (int j = 0; j < 4; ++j) a2[j] = (f32x4)0.0f;
#pragma unroll
  for (int ch = 0; ch < 2; ++ch)
#pragma unroll
    for (int k0 = 0; k0 < 128; k0 += 32) {
      bf16x8 af = *(const bf16x8*)(Pl + (wv * 16 + lm) * 264 + ch * 128 + k0 + qd * 8);
#pragma unroll
      for (int j = 0; j < 4; ++j) {
        bf16x8 bf = *(const bf16x8*)(Bw2 + ch * 8704 + (j * 16 + lm) * 136 + k0 + qd * 8);
        a2[j] = mfma16(af, bf, a2[j]);
      }
    }
#pragma unroll
  for (int j = 0; j < 4; ++j)
#pragma unroll
    for (int r = 0; r < 4; ++r) {
      long grow = m0 + wv * 16 + qd * 4 + r;
      long col = j * 16 + lm;
      oh[(bz * 4096 + grow) * 64 + col] = (bf16)(a2[j][r] / rs[r]);
    }
}

// depthwise conv residual
__global__ __launch_bounds__(256) void k_conv2(const bf16* __restrict__ v,
                                               const float* __restrict__ kern,
                                               bf16* __restrict__ oh) {
  __shared__ __align__(16) bf16 Vs[96 * 72];
  int bx = blockIdx.x;
  int bh = bx >> 6;
  int i0 = (bx & 63) * 64;
  int t = threadIdx.x;
  const bf16* vsrc = v + (long)bh * 262144;
#pragma unroll
  for (int c = 0; c < 3; ++c) {
    int idx = t + 256 * c;
    int r = idx >> 3, dc = (idx & 7) * 8;
    int grow = i0 + r - 16;
    bf16x8 val = (bf16x8)(bf16)0.0f;
    if (grow >= 0 && grow < 4096) val = *(const bf16x8*)(vsrc + (long)grow * 64 + dc);
    *(bf16x8*)(Vs + r * 72 + dc) = val;
  }
  __syncthreads();
  int dg = t & 15, rg = t >> 4;
  const float* kc = kern + (bh & 7) * 33;
  float acc[4][4] = {};
#pragma unroll
  for (int rr = 0; rr < 36; ++rr) {
    bf16x4 xv = *(const bf16x4*)(Vs + (rg * 4 + rr) * 72 + dg * 4);
    float x0 = (float)xv[0], x1 = (float)xv[1], x2 = (float)xv[2], x3 = (float)xv[3];
#pragma unroll
    for (int r = 0; r < 4; ++r) {
      int u = rr - r;
      if (u >= 0 && u < 33) {
        float kw = kc[u];
        acc[r][0] = fmaf(kw, x0, acc[r][0]);
        acc[r][1] = fmaf(kw, x1, acc[r][1]);
        acc[r][2] = fmaf(kw, x2, acc[r][2]);
        acc[r][3] = fmaf(kw, x3, acc[r][3]);
      }
    }
  }
  long base = ((long)bh * 4096 + i0 + rg * 4) * 64 + dg * 4;
#pragma unroll
  for (int r = 0; r < 4; ++r) {
    bf16x4 o = *(const bf16x4*)(oh + base + r * 64);
    bf16x4 w;
#pragma unroll
    for (int c = 0; c < 4; ++c) w[c] = (bf16)(acc[r][c] + (float)o[c]);
    *(bf16x4*)(oh + base + r * 64) = w;
  }
}

// ---------------- host ----------------
extern "C" void kernel_launch(void* const* d_in, const int* in_sizes, int n_in,
                              void* d_out, int out_size, void* d_ws, size_t ws_size,
                              hipStream_t stream) {
  const float* x     = (const float*)d_in[0];
  const float* w_qkv = (const float*)d_in[1];
  const float* w_out = (const float*)d_in[2];
  const float* b_out = (const float*)d_in[3];
  const float* res_k = (const float*)d_in[4];

  char* w = (char*)d_ws;
  bf16* qb  = (bf16*)(w);
  bf16* kb  = (bf16*)(w + 16777216);
  bf16* vb  = (bf16*)(w + 33554432);
  bf16* qlh = (bf16*)(w + 50331648);
  bf16* qll = (bf16*)(w + 51380224);
  bf16* klh = (bf16*)(w + 52428800);
  bf16* kll = (bf16*)(w + 53477376);
  bf16* A2h = (bf16*)(w + 54525952);
  bf16* A2l = (bf16*)(w + 58720256);
  bf16* zAh = (bf16*)(w + 62914560);
  bf16* zAl = (bf16*)(w + 67108864);
  bf16* zBh = (bf16*)(w + 71303168);
  bf16* zBl = (bf16*)(w + 75497472);
  bf16* yh  = (bf16*)(w + 79691776);
  bf16* yl  = (bf16*)(w + 83886080);
  bf16* wqt = (bf16*)(w + 88080384);        // [1536][512] bf16
  bf16* wot = (bf16*)(w + 89653248);        // [512][512] bf16
  bf16* y2h = (bf16*)(w + 96468992);        // y ping-pong buffer (4 MB)
  bf16* y2l = (bf16*)(w + 100663296);       // (4 MB)
  bf16* oh  = (bf16*)(w + 104857600);       // 16.8 MB bf16
  bf16* xb  = (bf16*)(w + 104857600);       // alias: xb used before oh is written
  float* a3vf = (float*)(w + 121634816);
  bf16* a3vh = (bf16*)(w + 123731968);
  bf16* a3vl = (bf16*)(w + 124780544);
  bf16* Wt   = (bf16*)(w + 125829120);
  float* rs3 = (float*)(w + 126877696);
  unsigned int* sc  = (unsigned int*)(w + 126910464);

  // prep: x cast + zeroing + weight transposes (single launch)
  k_prep<<<4352, 256, 0, stream>>>(x, xb, a3vf, rs3, sc, w_qkv, w_out, wqt, wot);

  // qkv projection: glds-staged bf16 gemm (BK=64), XCD-affine swizzle
  GP p{};
  p.A = xb; p.ldA = 512; p.B = wqt; p.ldB = 512; p.K = 512;
  p.C0 = qb; p.C1 = kb; p.C2 = vb;
  ggemm<0, EQKV, 1><<<1536, 256, 0, stream>>>(p);

  k_landmarks<<<8192, 64, 0, stream>>>(qb, kb, qlh, qll, klh, kll);

  // attn2 = softmax(ql @ kl^T), split-precision
  p = GP{};
  p.A = qlh; p.Al = qll; p.ldA = 64; p.sA = 16384;
  p.B = klh; p.Bl = kll; p.ldB = 64; p.sB = 16384; p.K = 64;
  p.C0 = A2h; p.C1 = A2l; p.sC = 65536; p.ldC = 256;
  mgemm<64, 256, 1, 0, 0, 1, EA2, 0><<<dim3(1, 4, 32), 256, 0, stream>>>(p);

  k_colsum<<<32, 256, 0, stream>>>(A2h, A2l, sc);
  k_zinit<<<dim3(4, 4, 32), 256, 0, stream>>>(A2h, A2l, sc, zAh, zAl);

  // a3v = softmax(ql @ k^T) @ v  — flash accumulation + normalize
  // 512 blocks (qt=4 x kt=4), KVBLK=128, T14 async-stage
  k_a3v<<<512, 256, 0, stream>>>(qlh, kb, vb, a3vf, rs3);
  k_a3vnorm<<<512, 256, 0, stream>>>(a3vf, rs3, a3vh, a3vl);

  // Newton-Schulz pinv: 1 init dispatch + 6 fused strip dispatches.
  // 1024 threads/block (16 waves/CU) for latency hiding.
  k_nsy0<<<256, 1024, 0, stream>>>(A2h, zAh, yh, yl);
  bf16 *zch = zAh, *zcl = zAl, *znh = zBh, *znl = zBl;
  bf16 *yih = yh, *yil = yl, *yoh = y2h, *yol = y2l;
  for (int it = 0; it < 6; ++it) {
    if (it < 3)
      k_ns4<0, 0><<<256, 1024, 0, stream>>>(A2h, A2l, yih, yil, zch, zcl, znh, znl, yoh, yol);
    else if (it == 3)
      k_ns4<0, 1><<<256, 1024, 0, stream>>>(A2h, A2l, yih, yil, zch, zcl, znh, znl, yoh, yol);
    else if (it == 4)
      k_ns4<1, 1><<<256, 1024, 0, stream>>>(A2h, A2l, yih, yil, zch, zcl, znh, znl, yoh, yol);
    else
      k_ns4<1, -1><<<256, 1024, 0, stream>>>(A2h, A2l, yih, yil, zch, zcl, znh, znl, yoh, yol);
    bf16* tmp;
    tmp = zch; zch = znh; znh = tmp;
    tmp = zcl; zcl = znl; znl = tmp;
    tmp = yih; yih = yoh; yoh = tmp;
    tmp = yil; yil = yol; yol = tmp;
  }

  // Wt = (z @ a3v)^T
  p = GP{};
  p.A = zch; p.Al = zcl; p.ldA = 256; p.sA = 65536;
  p.B = a3vh; p.Bl = a3vl; p.ldB = 64; p.sB = 16384; p.K = 256;
  p.C0 = Wt;
  mgemm<64, 64, 2, 0, 1, 1, EWT, 0><<<dim3(1, 4, 32), 256, 0, stream>>>(p);

  // oh = softmax(q @ kl^T) @ W (fused, T14 Wt prefetch), bf16 out
  k_attn1w<<<dim3(64, 1, 32), 256, 0, stream>>>(qb, klh, Wt, oh);

  // += depthwise conv residual
  k_conv2<<<2048, 256, 0, stream>>>(vb, res_k, oh);

  // out = gather(oh bf16) @ w_out + bias, glds-staged (BK=64), XCD-affine
  p = GP{};
  p.A = oh; p.ldA = 64; p.B = wot; p.ldB = 512; p.K = 512;
  p.C0 = d_out; p.bias = b_out;
  ggemm<3, EBIAS, 2><<<512, 256, 0, stream>>>(p);
}

// Round 13
// 426.973 us; speedup vs baseline: 1.0006x; 1.0006x over previous
//
#include <hip/hip_runtime.h>

// ---------------- problem constants ----------------
#define Nq   4096
#define DHq  64
#define Mq   256
#define BHq  32

using bf16 = __bf16;
using bf16x8 = __bf16 __attribute__((ext_vector_type(8)));
using bf16x4 = __bf16 __attribute__((ext_vector_type(4)));
using f32x4 = float __attribute__((ext_vector_type(4)));

__device__ __forceinline__ f32x4 mfma16(bf16x8 a, bf16x8 b, f32x4 c) {
  return __builtin_amdgcn_mfma_f32_16x16x32_bf16(a, b, c, 0, 0, 0);
}
__device__ __forceinline__ unsigned short f2bu(float f) {
  bf16 b = (bf16)f;
  return __builtin_bit_cast(unsigned short, b);
}
__device__ __forceinline__ void split_store(bf16* h, bf16* l, long idx, float v) {
  bf16 hi = (bf16)v;
  h[idx] = hi;
  l[idx] = (bf16)(v - (float)hi);
}

// async global->LDS, 16B per lane; LDS dest = wave-uniform base + lane*16
typedef const __attribute__((address_space(1))) void* gas_t;
typedef __attribute__((address_space(3))) void* las_t;
__device__ __forceinline__ void glds16(const bf16* g, bf16* l) {
  __builtin_amdgcn_global_load_lds((gas_t)g, (las_t)l, 16, 0, 0);
}

// Stage a ROWS x 32 bf16 tile into LDS, row stride 40 bf16 (80 B).
// SRC: 0 = bf16 row-major, 1 = f32 row-major
template<int ROWS, int SRC>
__device__ __forceinline__ void stageA(const void* src, long ld, long row0, int k0,
                                       bf16* dst, int t) {
#pragma unroll
  for (int c = 0; c < ROWS / 64; ++c) {
    int idx = t + 256 * c;
    int r = idx >> 2;
    int kc = (idx & 3) << 3;
    bf16x8 val;
    if constexpr (SRC == 0) {
      val = *(const bf16x8*)((const bf16*)src + (row0 + r) * ld + k0 + kc);
    } else {
      const float* s = (const float*)src + (row0 + r) * ld + k0 + kc;
      float4 a = *(const float4*)s;
      float4 b = *(const float4*)(s + 4);
      val[0]=(bf16)a.x; val[1]=(bf16)a.y; val[2]=(bf16)a.z; val[3]=(bf16)a.w;
      val[4]=(bf16)b.x; val[5]=(bf16)b.y; val[6]=(bf16)b.z; val[7]=(bf16)b.w;
    }
    *(bf16x8*)(dst + r * 40 + kc) = val;
  }
}

// Stage 32 x COLS tile of row-major [K][N] B into word-LDS [COLS][20 words].
template<int COLS, bool F32>
__device__ __forceinline__ void stageBN(const void* src, long ld, long n0, int k0,
                                        unsigned int* dst, int t) {
  int kp = t >> 4;
  int nb = (t & 15) << 2;
#pragma unroll
  for (int g = 0; g < COLS / 64; ++g) {
    int n = nb + (g << 6);
    unsigned int w0, w1, w2, w3;
    if constexpr (F32) {
      const float* s0 = (const float*)src + (long)(k0 + 2 * kp) * ld + n0 + n;
      const float* s1 = s0 + ld;
      float4 a = *(const float4*)s0;
      float4 b = *(const float4*)s1;
      w0 = f2bu(a.x) | ((unsigned)f2bu(b.x) << 16);
      w1 = f2bu(a.y) | ((unsigned)f2bu(b.y) << 16);
      w2 = f2bu(a.z) | ((unsigned)f2bu(b.z) << 16);
      w3 = f2bu(a.w) | ((unsigned)f2bu(b.w) << 16);
    } else {
      const unsigned short* s0 = (const unsigned short*)src + (long)(k0 + 2 * kp) * ld + n0 + n;
      const unsigned short* s1 = s0 + ld;
      ushort4 a = *(const ushort4*)s0;
      ushort4 b = *(const ushort4*)s1;
      w0 = a.x | ((unsigned)b.x << 16);
      w1 = a.y | ((unsigned)b.y << 16);
      w2 = a.z | ((unsigned)b.z << 16);
      w3 = a.w | ((unsigned)b.w << 16);
    }
    dst[(n + 0) * 20 + kp] = w0;
    dst[(n + 1) * 20 + kp] = w1;
    dst[(n + 2) * 20 + kp] = w2;
    dst[(n + 3) * 20 + kp] = w3;
  }
}

#define EQKV 0
#define EA2 1
#define EWT 8
#define EBIAS 9

struct GP {
  const void* A; const void* Al;
  const void* B; const void* Bl;
  long ldA, ldB, sA, sB;
  int K;
  void* C0; void* C1; void* C2;
  long sC, ldC;
  const void* x0; const void* x1;
  const float* bias;
};

// ---------------- mgemm (kept for attn2 / Wt small gemms) ----------------
template<int BM, int BN, int WX, int ASRC, int BMODE, int SPLIT, int EPI, int SWZ>
__global__ __launch_bounds__(256, 2) void mgemm(GP p) {
  constexpr int WY = 4 / WX;
  constexpr int TM = BM / WY, TN = BN / WX;
  constexpr int IT = TM / 16, JT = TN / 16;
  constexpr int AB = (SPLIT ? 2 : 1) * BM * 80;
  constexpr int BB = (SPLIT ? 2 : 1) * BN * 80;
  __shared__ __align__(16) char Lbuf[AB + BB];
  bf16* AsL = (bf16*)Lbuf;
  unsigned int* BsL = (unsigned int*)(Lbuf + AB);
  int t = threadIdx.x;
  int wv = t >> 6, lane = t & 63;
  int wy = wv / WX, wx = wv % WX;
  int qd = lane >> 4, lm = lane & 15;
  long bz = blockIdx.z, m0 = (long)blockIdx.y * BM, n0 = (long)blockIdx.x * BN;

  const void* Ap = (const bf16*)p.A + bz * p.sA;
  const void* Alp = nullptr;
  if constexpr (SPLIT) Alp = (const bf16*)p.Al + bz * p.sA;
  const void* Bp = (const bf16*)p.B + bz * p.sB;
  const void* Blp = nullptr;
  if constexpr (SPLIT) Blp = (const bf16*)p.Bl + bz * p.sB;

  f32x4 acc[IT][JT];
#pragma unroll
  for (int i = 0; i < IT; ++i)
#pragma unroll
    for (int j = 0; j < JT; ++j) acc[i][j] = (f32x4)0.0f;

  for (int k0 = 0; k0 < p.K; k0 += 32) {
    stageA<BM, ASRC>(Ap, p.ldA, m0, k0, AsL, t);
    if constexpr (SPLIT) stageA<BM, 0>(Alp, p.ldA, m0, k0, AsL + BM * 40, t);
    if constexpr (BMODE == 0) {
      stageA<BN, 0>(Bp, p.ldB, n0, k0, (bf16*)BsL, t);
      if constexpr (SPLIT) stageA<BN, 0>(Blp, p.ldB, n0, k0, (bf16*)BsL + BN * 40, t);
    } else {
      stageBN<BN, false>(Bp, p.ldB, n0, k0, BsL, t);
      if constexpr (SPLIT) stageBN<BN, false>(Blp, p.ldB, n0, k0, BsL + BN * 20, t);
    }
    __syncthreads();
    bf16x8 af[IT], afl[IT];
#pragma unroll
    for (int i = 0; i < IT; ++i) {
      int m = wy * TM + i * 16 + lm;
      af[i] = *(const bf16x8*)(AsL + m * 40 + qd * 8);
      if constexpr (SPLIT) afl[i] = *(const bf16x8*)(AsL + BM * 40 + m * 40 + qd * 8);
    }
#pragma unroll
    for (int j = 0; j < JT; ++j) {
      int n = wx * TN + j * 16 + lm;
      bf16x8 bf, bfl;
      if constexpr (BMODE == 0) {
        bf = *(const bf16x8*)((const bf16*)BsL + n * 40 + qd * 8);
        if constexpr (SPLIT) bfl = *(const bf16x8*)((const bf16*)BsL + BN * 40 + n * 40 + qd * 8);
      } else {
        bf = *(const bf16x8*)((const bf16*)(BsL + n * 20 + qd * 4));
        if constexpr (SPLIT) bfl = *(const bf16x8*)((const bf16*)(BsL + BN * 20 + n * 20 + qd * 4));
      }
#pragma unroll
      for (int i = 0; i < IT; ++i) {
        acc[i][j] = mfma16(af[i], bf, acc[i][j]);
        if constexpr (SPLIT) {
          acc[i][j] = mfma16(af[i], bfl, acc[i][j]);
          acc[i][j] = mfma16(afl[i], bf, acc[i][j]);
        }
      }
    }
    __syncthreads();
  }

  if constexpr (EPI == EA2) {
#pragma unroll
    for (int r = 0; r < 4; ++r) {
      long row = m0 + wy * TM + qd * 4 + r;
      float e[JT];
      float s = 0.f;
#pragma unroll
      for (int j = 0; j < JT; ++j) { e[j] = __expf(acc[0][j][r]); s += e[j]; }
      s += __shfl_xor(s, 1); s += __shfl_xor(s, 2);
      s += __shfl_xor(s, 4); s += __shfl_xor(s, 8);
      float inv = 1.0f / s;
#pragma unroll
      for (int j = 0; j < JT; ++j) {
        long col = n0 + j * 16 + lm;
        split_store((bf16*)p.C0, (bf16*)p.C1, bz * p.sC + row * p.ldC + col, e[j] * inv);
      }
    }
  } else {
#pragma unroll
    for (int i = 0; i < IT; ++i)
#pragma unroll
      for (int j = 0; j < JT; ++j)
#pragma unroll
        for (int r = 0; r < 4; ++r) {
          long row = m0 + wy * TM + i * 16 + qd * 4 + r;
          long col = n0 + wx * TN + j * 16 + lm;
          float v = acc[i][j][r];
          if constexpr (EPI == EWT) {
            ((bf16*)p.C0)[bz * 16384 + col * 256 + row] = (bf16)v;
          }
        }
  }
}

// ---------------- glds-staged 128x128 gemm (QKV + out-proj, BK=64) ----------------
template<int ASRC, int EPI, int SWZ>
__global__ __launch_bounds__(256, 3) void ggemm(GP p) {
  __shared__ __align__(64) bf16 AsL[2][128 * 32];
  __shared__ __align__(64) bf16 BsL[2][128 * 32];
  int t = threadIdx.x, wv = t >> 6, lane = t & 63;
  int wy = wv >> 1, wx = wv & 1;
  int qd = lane >> 4, lm = lane & 15;
  long m0, n0;
  if constexpr (SWZ == 1) {
    int b = blockIdx.x, xcd = b & 7, s = b >> 3;
    m0 = (long)(xcd * 16 + s / 12) * 128; n0 = (long)(s % 12) * 128;
  } else {
    int b = blockIdx.x, xcd = b & 7, s = b >> 3;
    m0 = (long)(xcd * 16 + (s >> 2)) * 128; n0 = (long)(s & 3) * 128;
  }
  const bf16* A = (const bf16*)p.A;
  const bf16* B = (const bf16*)p.B;

  f32x4 acc[4][4];
#pragma unroll
  for (int i = 0; i < 4; ++i)
#pragma unroll
    for (int j = 0; j < 4; ++j) acc[i][j] = (f32x4)0.0f;

  int rsub = lane >> 2;           // 0..15 row within 16-row group
  int kc = (lane & 3) << 3;       // 0,8,16,24 bf16 col offset
  for (int k0 = 0; k0 < p.K; k0 += 64) {
#pragma unroll
    for (int half = 0; half < 2; ++half) {
      int kk = k0 + half * 32;
#pragma unroll
      for (int e = 0; e < 2; ++e) {
        int br = wv * 32 + e * 16;          // wave-uniform base row
        long rA = m0 + br + rsub;
        const bf16* gA;
        if constexpr (ASRC == 0) {
          gA = A + rA * p.ldA + kk + kc;
        } else {
          long bb = rA >> 12, ii = rA & 4095;
          int k = kk + kc;
          long h = k >> 6, d = k & 63;
          gA = A + (((bb * 8 + h) * 4096 + ii) * 64 + d);
        }
        glds16(gA, AsL[half] + br * 32);
        const bf16* gB = B + (n0 + br + rsub) * p.ldB + kk + kc;
        glds16(gB, BsL[half] + br * 32);
      }
    }
    __syncthreads();
#pragma unroll
    for (int half = 0; half < 2; ++half) {
      bf16x8 af[4];
#pragma unroll
      for (int i = 0; i < 4; ++i)
        af[i] = *(const bf16x8*)(AsL[half] + (wy * 64 + i * 16 + lm) * 32 + qd * 8);
#pragma unroll
      for (int j = 0; j < 4; ++j) {
        bf16x8 bv = *(const bf16x8*)(BsL[half] + (wx * 64 + j * 16 + lm) * 32 + qd * 8);
#pragma unroll
        for (int i = 0; i < 4; ++i) acc[i][j] = mfma16(af[i], bv, acc[i][j]);
      }
    }
    __syncthreads();
  }

#pragma unroll
  for (int i = 0; i < 4; ++i)
#pragma unroll
    for (int j = 0; j < 4; ++j)
#pragma unroll
      for (int r = 0; r < 4; ++r) {
        long row = m0 + wy * 64 + i * 16 + qd * 4 + r;
        long col = n0 + wx * 64 + j * 16 + lm;
        float v = acc[i][j][r];
        if constexpr (EPI == EQKV) {
          int part = (int)(col >> 9);
          long h = (col >> 6) & 7, d = col & 63;
          long bb = row >> 12, ii = row & 4095;
          float scv = part == 0 ? 0.125f : 1.0f;
          bf16* dst = part == 0 ? (bf16*)p.C0 : (part == 1 ? (bf16*)p.C1 : (bf16*)p.C2);
          dst[((bb * 8 + h) * 4096 + ii) * 64 + d] = (bf16)(v * scv);
        } else {
          ((float*)p.C0)[row * 512 + col] = v + p.bias[col];
        }
      }
}

// ---------------- fused prep: x->bf16 cast + zeroing + weight transposes ------
__global__ __launch_bounds__(256) void k_prep(const float* __restrict__ x,
                                              bf16* __restrict__ xb,
                                              float* a3vf, float* rs3, unsigned int* sc,
                                              const float* __restrict__ wq,
                                              const float* __restrict__ wo,
                                              bf16* __restrict__ wqt,
                                              bf16* __restrict__ wot) {
  __shared__ float T[64][65];
  int bid = blockIdx.x, t = threadIdx.x;
  if (bid < 4096) {
    long i = (long)bid * 256 + t;
    long e = i * 8;
    float4 a = *(const float4*)(x + e);
    float4 b = *(const float4*)(x + e + 4);
    bf16x8 v;
    v[0]=(bf16)a.x; v[1]=(bf16)a.y; v[2]=(bf16)a.z; v[3]=(bf16)a.w;
    v[4]=(bf16)b.x; v[5]=(bf16)b.y; v[6]=(bf16)b.z; v[7]=(bf16)b.w;
    *(bf16x8*)(xb + e) = v;
    if (i < 524288) a3vf[i] = 0.f;
    if (i < 8192) rs3[i] = 0.f;
    if (i == 0) sc[0] = 0u;
  } else {
    int w = bid - 4096;           // 0..255
    int bx = w >> 3, ti = w & 7;
    const float* src; bf16* dst; int N, tj;
    if (bx < 24) { src = wq; dst = wqt; N = 1536; tj = bx; }
    else         { src = wo; dst = wot; N = 512;  tj = bx - 24; }
    int c = t & 63, r0 = t >> 6;
#pragma unroll
    for (int rr = 0; rr < 16; ++rr) {
      int r = r0 * 16 + rr;
      T[r][c] = src[(long)(ti * 64 + r) * N + tj * 64 + c];
    }
    __syncthreads();
#pragma unroll
    for (int rr = 0; rr < 16; ++rr) {
      int n = r0 * 16 + rr;
      dst[(long)(tj * 64 + n) * 512 + ti * 64 + c] = (bf16)T[c][n];
    }
  }
}

// ---------------- strip-resident Newton-Schulz (32-col strips, 256 blocks) ----
// 1024 threads/block (16 waves/CU); verified round 8.
#define SBW 132

__device__ __forceinline__ void stageBS32(const bf16* src, long n0, int k0,
                                          unsigned int* dst, int t) {
  int kp = t >> 3, nb = (t & 7) << 2;
  const unsigned short* s0 = (const unsigned short*)src + (long)(k0 + 2 * kp) * 256 + n0 + nb;
  const unsigned short* s1 = s0 + 256;
  ushort4 a = *(const ushort4*)s0;
  ushort4 b = *(const ushort4*)s1;
  int wb = (k0 >> 1) + kp;
  dst[(nb + 0) * SBW + wb] = a.x | ((unsigned)b.x << 16);
  dst[(nb + 1) * SBW + wb] = a.y | ((unsigned)b.y << 16);
  dst[(nb + 2) * SBW + wb] = a.z | ((unsigned)b.z << 16);
  dst[(nb + 3) * SBW + wb] = a.w | ((unsigned)b.w << 16);
}

// C rows [w*16, w*16+16) x 32 cols = A-rows(global) @ B_strip(LDS). 16 waves.
template<int SPLIT>
__device__ __forceinline__ void sgemm32(const bf16* Ah, const bf16* Al,
                                        const unsigned int* Bs, const unsigned int* Bsl,
                                        int w, int lane, f32x4 acc[2]) {
  int qd = lane >> 4, lm = lane & 15;
  acc[0] = (f32x4)0.0f;
  acc[1] = (f32x4)0.0f;
#pragma unroll 2
  for (int k0 = 0; k0 < 256; k0 += 32) {
    long m = w * 16 + lm;
    bf16x8 af = *(const bf16x8*)(Ah + m * 256 + k0 + qd * 8);
    bf16x8 afl;
    if constexpr (SPLIT) afl = *(const bf16x8*)(Al + m * 256 + k0 + qd * 8);
#pragma unroll
    for (int j = 0; j < 2; ++j) {
      bf16x8 bv = *(const bf16x8*)((const bf16*)(Bs + (j * 16 + lm) * SBW + (k0 >> 1) + qd * 4));
      acc[j] = mfma16(af, bv, acc[j]);
      if constexpr (SPLIT) {
        bf16x8 bl = *(const bf16x8*)((const bf16*)(Bsl + (j * 16 + lm) * SBW + (k0 >> 1) + qd * 4));
        acc[j] = mfma16(af, bl, acc[j]);
        acc[j] = mfma16(afl, bv, acc[j]);
      }
    }
  }
}

// pack 4 rows (R0..R0+3) of column col into transposed strip LDS (h, and l residual)
template<int HASL>
__device__ __forceinline__ void packStrip(unsigned int* Sh, unsigned int* Sl,
                                          int col, int R0, const float* v) {
  unsigned int* Wp = Sh + col * SBW + (R0 >> 1);
  Wp[0] = f2bu(v[0]) | ((unsigned)f2bu(v[1]) << 16);
  Wp[1] = f2bu(v[2]) | ((unsigned)f2bu(v[3]) << 16);
  if constexpr (HASL) {
    unsigned int* Wq = Sl + col * SBW + (R0 >> 1);
    Wq[0] = f2bu(v[0] - (float)(bf16)v[0]) | ((unsigned)f2bu(v[1] - (float)(bf16)v[1]) << 16);
    Wq[1] = f2bu(v[2] - (float)(bf16)v[2]) | ((unsigned)f2bu(v[3] - (float)(bf16)v[3]) << 16);
  }
}

// XCD-affine block -> (bh, strip) mapping
__device__ __forceinline__ void nsmap(int b, long& bh, long& js) {
  int xcd = b & 7, s = b >> 3;
  bh = xcd * 4 + (s >> 3);
  js = (long)(s & 7) * 32;
}

// y0 = A2 @ z0 (non-split inputs, split-stored output)
__global__ __launch_bounds__(1024) void k_nsy0(const bf16* __restrict__ A2h,
                                               const bf16* __restrict__ zh,
                                               bf16* __restrict__ yh, bf16* __restrict__ yl) {
  __shared__ __align__(16) unsigned int Bs[32 * SBW];
  int b = blockIdx.x, t = threadIdx.x;
  long bh, js;
  nsmap(b, bh, js);
  const bf16* Ah = A2h + bh * 65536;
  const bf16* Bz = zh + bh * 65536;
  if (t < 128) {
#pragma unroll
    for (int k0 = 0; k0 < 256; k0 += 32) stageBS32(Bz, js, k0, Bs, t);
  }
  __syncthreads();
  int w = t >> 6, lane = t & 63, qd = lane >> 4, lm = lane & 15;
  f32x4 acc[2];
  sgemm32<0>(Ah, Ah, Bs, Bs, w, lane, acc);
  bf16* yhb = yh + bh * 65536;
  bf16* ylb = yl + bh * 65536;
#pragma unroll
  for (int j = 0; j < 2; ++j)
#pragma unroll
    for (int r = 0; r < 4; ++r) {
      long row = w * 16 + qd * 4 + r;
      long col = js + j * 16 + lm;
      split_store(yhb, ylb, row * 256 + col, acc[j][r]);
    }
}

// One NS iteration for one 32-col strip (see round-8 comments).
template<int SPLIT, int YS>
__global__ __launch_bounds__(1024) void k_ns4(
    const bf16* __restrict__ A2h, const bf16* __restrict__ A2l,
    const bf16* __restrict__ yih, const bf16* __restrict__ yil,
    const bf16* __restrict__ zh_, const bf16* __restrict__ zl_,
    bf16* __restrict__ znh_, bf16* __restrict__ znl_,
    bf16* __restrict__ yoh_, bf16* __restrict__ yol_) {
  constexpr int P0 = SPLIT ? 2 : 1;
  constexpr int P1 = (SPLIT || YS == 1) ? 2 : 1;
  __shared__ __align__(16) unsigned int S0[P0][32 * SBW];
  __shared__ __align__(16) unsigned int S1[P1][32 * SBW];
  int b = blockIdx.x, t = threadIdx.x;
  long bh, js;
  nsmap(b, bh, js);
  const bf16* yH = yih + bh * 65536;
  const bf16* yL = yil + bh * 65536;
  const bf16* zH = zh_ + bh * 65536;
  const bf16* zL = zl_ + bh * 65536;
  const bf16* aH = A2h + bh * 65536;
  const bf16* aL = A2l + bh * 65536;
  unsigned int* S0l = S0[P0 - 1];
  unsigned int* S1l = S1[P1 - 1];
  if (t < 128) {
#pragma unroll
    for (int k0 = 0; k0 < 256; k0 += 32) {
      stageBS32(yH, js, k0, S0[0], t);
      if constexpr (SPLIT) stageBS32(yL, js, k0, S0l, t);
    }
  }
  __syncthreads();
  int w = t >> 6, lane = t & 63, qd = lane >> 4, lm = lane & 15;
  f32x4 acc[2];

  // gemm1: bb = 15I - 7y + y @ y_strip -> S1
  sgemm32<SPLIT>(yH, yL, S0[0], S0l, w, lane, acc);
#pragma unroll
  for (int j = 0; j < 2; ++j) {
    int R0 = w * 16 + qd * 4;
    int col = j * 16 + lm;
    float v[4];
#pragma unroll
    for (int r = 0; r < 4; ++r) {
      long row = R0 + r;
      long ix = row * 256 + js + col;
      float yv = (float)yH[ix] + (float)yL[ix];
      v[r] = ((row == js + col) ? 15.0f : 0.0f) - 7.0f * yv + acc[j][r];
    }
    packStrip<SPLIT>(S1[0], S1l, col, R0, v);
  }
  __syncthreads();

  // gemm2: cc = 13I - y @ bb_strip -> S0
  sgemm32<SPLIT>(yH, yL, S1[0], S1l, w, lane, acc);
#pragma unroll
  for (int j = 0; j < 2; ++j) {
    int R0 = w * 16 + qd * 4;
    int col = j * 16 + lm;
    float v[4];
#pragma unroll
    for (int r = 0; r < 4; ++r)
      v[r] = (((long)(R0 + r) == js + col) ? 13.0f : 0.0f) - acc[j][r];
    packStrip<SPLIT>(S0[0], S0l, col, R0, v);
  }
  __syncthreads();

  // gemm3: zn = 0.25 * z @ cc_strip -> global split [+ pack S1]
  sgemm32<SPLIT>(zH, zL, S0[0], S0l, w, lane, acc);
  bf16* zoh = znh_ + bh * 65536;
  bf16* zol = znl_ + bh * 65536;
#pragma unroll
  for (int j = 0; j < 2; ++j) {
    int R0 = w * 16 + qd * 4;
    int col = j * 16 + lm;
    float v[4];
#pragma unroll
    for (int r = 0; r < 4; ++r) {
      v[r] = 0.25f * acc[j][r];
      split_store(zoh, zol, (long)(R0 + r) * 256 + js + col, v[r]);
    }
    if constexpr (YS >= 0) packStrip<(YS == 1) ? 1 : 0>(S1[0], S1l, col, R0, v);
  }

  // gemm4: y' = A2 @ zn_strip -> global split
  if constexpr (YS >= 0) {
    __syncthreads();
    sgemm32<(YS == 1) ? 1 : 0>(aH, aL, S1[0], S1l, w, lane, acc);
    bf16* yoh = yoh_ + bh * 65536;
    bf16* yol = yol_ + bh * 65536;
#pragma unroll
    for (int j = 0; j < 2; ++j)
#pragma unroll
      for (int r = 0; r < 4; ++r) {
        long row = w * 16 + qd * 4 + r;
        long col = js + j * 16 + lm;
        split_store(yoh, yol, row * 256 + col, acc[j][r]);
      }
  }
}

// ---------------- flash a3v (kt=4, 512 blocks, KVBLK=128, T14) ----------------
// Verified round 11: 8 iterations x 3 barriers, 32 MFMA between barrier pairs.
__device__ __forceinline__ void loadKrow4(const bf16* ks_, int t, bf16x8 kr[4]) {
#pragma unroll
  for (int c = 0; c < 4; ++c) {
    int idx = t + 256 * c;
    int r = idx >> 3, dc = (idx & 7) * 8;
    kr[c] = *(const bf16x8*)(ks_ + r * 64 + dc);
  }
}
__device__ __forceinline__ void writeKrow4(bf16* kS, int t, const bf16x8 kr[4]) {
#pragma unroll
  for (int c = 0; c < 4; ++c) {
    int idx = t + 256 * c;
    int r = idx >> 3, dc = (idx & 7) * 8;
    *(bf16x8*)(kS + r * 72 + dc) = kr[c];
  }
}
__device__ __forceinline__ void loadVhalf(const bf16* vs_, int k0, int t,
                                          ushort4& a, ushort4& b) {
  int kp = t >> 4, nb = (t & 15) << 2;
  const unsigned short* s0 = (const unsigned short*)vs_ + (long)(k0 + 2 * kp) * 64 + nb;
  a = *(const ushort4*)s0;
  b = *(const ushort4*)(s0 + 64);
}
__device__ __forceinline__ void writeVhalf(unsigned int* dst, int t, ushort4 a, ushort4 b) {
  int kp = t >> 4, nb = (t & 15) << 2;
  dst[(nb + 0) * 20 + kp] = a.x | ((unsigned)b.x << 16);
  dst[(nb + 1) * 20 + kp] = a.y | ((unsigned)b.y << 16);
  dst[(nb + 2) * 20 + kp] = a.z | ((unsigned)b.z << 16);
  dst[(nb + 3) * 20 + kp] = a.w | ((unsigned)b.w << 16);
}

__global__ __launch_bounds__(256, 2) void k_a3v(const bf16* __restrict__ qlh,
                                                const bf16* __restrict__ kb,
                                                const bf16* __restrict__ vb,
                                                float* __restrict__ a3vf,
                                                float* __restrict__ rs3) {
  __shared__ __align__(16) char L[66048];
  bf16* qlS = (bf16*)L;                           // [64][72]
  bf16* kS  = (bf16*)(L + 9216);                  // [128][72]
  bf16* PA  = (bf16*)(L + 27648);                 // [64][136]
  unsigned int* vBb = (unsigned int*)(L + 45056); // 4 x [64][20] words
  float* rsL = (float*)(L + 65536);               // [64][2]
  int b = blockIdx.x, t = threadIdx.x;
  int xcd = b & 7, s = b >> 3;
  int strip = xcd * 16 + (s >> 2);
  int qt = s & 3;
  long bz = strip >> 2;
  int kt = strip & 3;
  int wv = t >> 6, lane = t & 63, qd = lane >> 4, lm = lane & 15;
  int wy = wv >> 1, wx = wv & 1;
  const bf16* qlp = qlh + bz * 16384 + qt * 64 * 64;
#pragma unroll
  for (int c = 0; c < 2; ++c) {
    int idx = t + 256 * c;
    int r = idx >> 3, dc = (idx & 7) * 8;
    *(bf16x8*)(qlS + r * 72 + dc) = *(const bf16x8*)(qlp + r * 64 + dc);
  }
  const bf16* kb_ = kb + bz * 262144 + (long)kt * 65536;
  const bf16* vb_ = vb + bz * 262144 + (long)kt * 65536;
  f32x4 accO[2][2];
  float rsum[2][4];
#pragma unroll
  for (int i = 0; i < 2; ++i) {
#pragma unroll
    for (int j = 0; j < 2; ++j) accO[i][j] = (f32x4)0.0f;
#pragma unroll
    for (int r = 0; r < 4; ++r) rsum[i][r] = 0.f;
  }
  // prefetch tt=0 into registers (128 K rows, 128 V rows)
  bf16x8 kr[4];
  ushort4 va[4], vbq[4];
  loadKrow4(kb_, t, kr);
#pragma unroll
  for (int q = 0; q < 4; ++q) loadVhalf(vb_, q * 32, t, va[q], vbq[q]);
  for (int tt = 0; tt < 8; ++tt) {
    __syncthreads();
    writeKrow4(kS, t, kr);
#pragma unroll
    for (int q = 0; q < 4; ++q) writeVhalf(vBb + q * 1280, t, va[q], vbq[q]);
    __syncthreads();
    if (tt < 7) {   // issue next tile's loads; they complete under QK/SM/PV
      const bf16* ks2 = kb_ + (tt + 1) * 8192;
      const bf16* vs2 = vb_ + (tt + 1) * 8192;
      loadKrow4(ks2, t, kr);
#pragma unroll
      for (int q = 0; q < 4; ++q) loadVhalf(vs2, q * 32, t, va[q], vbq[q]);
    }
    f32x4 s2[2][4];
#pragma unroll
    for (int i = 0; i < 2; ++i)
#pragma unroll
      for (int j = 0; j < 4; ++j) s2[i][j] = (f32x4)0.0f;
#pragma unroll
    for (int ks = 0; ks < 2; ++ks) {
      bf16x8 af[2];
#pragma unroll
      for (int i = 0; i < 2; ++i)
        af[i] = *(const bf16x8*)(qlS + (wy * 32 + i * 16 + lm) * 72 + ks * 32 + qd * 8);
#pragma unroll
      for (int j = 0; j < 4; ++j) {
        bf16x8 bfv = *(const bf16x8*)(kS + (wx * 64 + j * 16 + lm) * 72 + ks * 32 + qd * 8);
#pragma unroll
        for (int i = 0; i < 2; ++i) s2[i][j] = mfma16(af[i], bfv, s2[i][j]);
      }
    }
#pragma unroll
    for (int i = 0; i < 2; ++i)
#pragma unroll
      for (int r = 0; r < 4; ++r) {
        int row = wy * 32 + i * 16 + qd * 4 + r;
        float cs = 0.f;
#pragma unroll
        for (int j = 0; j < 4; ++j) {
          float e = __expf(s2[i][j][r]);
          PA[row * 136 + wx * 64 + j * 16 + lm] = (bf16)e;
          cs += e;
        }
        cs += __shfl_xor(cs, 1); cs += __shfl_xor(cs, 2);
        cs += __shfl_xor(cs, 4); cs += __shfl_xor(cs, 8);
        rsum[i][r] += cs;
      }
    __syncthreads();
#pragma unroll
    for (int ks = 0; ks < 4; ++ks) {
      const unsigned int* vB = vBb + ks * 1280;
      bf16x8 af[2];
#pragma unroll
      for (int i = 0; i < 2; ++i)
        af[i] = *(const bf16x8*)(PA + (wy * 32 + i * 16 + lm) * 136 + ks * 32 + qd * 8);
#pragma unroll
      for (int j = 0; j < 2; ++j) {
        bf16x8 bfv = *(const bf16x8*)((const bf16*)(vB + (wx * 32 + j * 16 + lm) * 20) + qd * 8);
#pragma unroll
        for (int i = 0; i < 2; ++i) accO[i][j] = mfma16(af[i], bfv, accO[i][j]);
      }
    }
  }
  if (lm == 0) {
#pragma unroll
    for (int i = 0; i < 2; ++i)
#pragma unroll
      for (int r = 0; r < 4; ++r)
        rsL[(wy * 32 + i * 16 + qd * 4 + r) * 2 + wx] = rsum[i][r];
  }
  __syncthreads();
  if (t < 64) atomicAdd(&rs3[bz * 256 + qt * 64 + t], rsL[t * 2] + rsL[t * 2 + 1]);
#pragma unroll
  for (int i = 0; i < 2; ++i)
#pragma unroll
    for (int j = 0; j < 2; ++j)
#pragma unroll
      for (int r = 0; r < 4; ++r) {
        long row = bz * 256 + qt * 64 + wy * 32 + i * 16 + qd * 4 + r;
        long col = wx * 32 + j * 16 + lm;
        atomicAdd(&a3vf[row * 64 + col], accO[i][j][r]);
      }
}

__global__ void k_a3vnorm(const float* __restrict__ a3vf, const float* __restrict__ rs3,
                          bf16* __restrict__ a3vh, bf16* __restrict__ a3vl) {
  long e0 = ((long)blockIdx.x * 256 + threadIdx.x) * 4;
  float4 vv = *(const float4*)&a3vf[e0];
  float inv = 1.0f / rs3[e0 >> 6];
  split_store(a3vh, a3vl, e0 + 0, vv.x * inv);
  split_store(a3vh, a3vl, e0 + 1, vv.y * inv);
  split_store(a3vh, a3vl, e0 + 2, vv.z * inv);
  split_store(a3vh, a3vl, e0 + 3, vv.w * inv);
}

// ---------------- small kernels ----------------
__global__ void k_landmarks(const bf16* q, const bf16* k, bf16* qlh, bf16* qll,
                            bf16* klh, bf16* kll) {
  int bm = blockIdx.x;
  int bh = bm >> 8, mi = bm & 255;
  int d = threadIdx.x;
  const bf16* qp = q + ((long)bh * 4096 + mi * 16) * 64 + d;
  const bf16* kp = k + ((long)bh * 4096 + mi * 16) * 64 + d;
  float sq = 0.f, sk = 0.f;
#pragma unroll
  for (int tt = 0; tt < 16; ++tt) { sq += (float)qp[tt * 64]; sk += (float)kp[tt * 64]; }
  sq *= 0.0625f; sk *= 0.0625f;
  long o = (long)bh * 16384 + mi * 64 + d;
  split_store(qlh, qll, o, sq);
  split_store(klh, kll, o, sk);
}

__global__ __launch_bounds__(256) void k_colsum(const bf16* A2h, const bf16* A2l,
                                                unsigned int* sc) {
  int bh = blockIdx.x, j = threadIdx.x;
  const bf16* ph = A2h + (long)bh * 65536 + j;
  const bf16* pl = A2l + (long)bh * 65536 + j;
  float s = 0.f;
  for (int i = 0; i < 256; ++i) s += (float)ph[i * 256] + (float)pl[i * 256];
  __shared__ float red[256];
  red[j] = s; __syncthreads();
  for (int o = 128; o > 0; o >>= 1) {
    if (j < o) red[j] = fmaxf(red[j], red[j + o]);
    __syncthreads();
  }
  if (j == 0) atomicMax(sc, __float_as_uint(red[0]));
}

__global__ __launch_bounds__(256) void k_zinit(const bf16* A2h, const bf16* A2l,
                                               const unsigned int* sc, bf16* zh, bf16* zl) {
  __shared__ float T[64][65];
  int bh = blockIdx.z, ti = blockIdx.y, tj = blockIdx.x;
  int t = threadIdx.x;
  int c = t & 63, r0 = t >> 6;
  long base = (long)bh * 65536;
  float inv = 1.0f / __uint_as_float(sc[0]);
#pragma unroll
  for (int rr = 0; rr < 16; ++rr) {
    int r = r0 * 16 + rr;
    long idx = base + (long)(ti * 64 + r) * 256 + tj * 64 + c;
    T[r][c] = (float)A2h[idx] + (float)A2l[idx];
  }
  __syncthreads();
#pragma unroll
  for (int rr = 0; rr < 16; ++rr) {
    int jl = r0 * 16 + rr;
    float v = T[c][jl] * inv;
    long o = base + (long)(tj * 64 + jl) * 256 + ti * 64 + c;
    split_store(zh, zl, o, v);
  }
}

// fused: oh = softmax(q @ kl^T) @ W  (bf16 out), Wt [bh][64][256]
// Stage-2 single-barrier structure (round 12), but the Wt register prefetch is
// issued AFTER stage-1's final barrier: stage-1 contains vmcnt(0)-draining
// barriers that would serialize an entry-issued prefetch (round-12 lesson).
// The softmax below (64 exp + 20 shfl, no barriers) is the T14 hiding window.
__global__ __launch_bounds__(256, 2) void k_attn1w(const bf16* qb, const bf16* klb,
                                                   const bf16* Wt, bf16* oh) {
  __shared__ __align__(16) char L[68608];
  bf16* Aq = (bf16*)L;             // [64][40]
  bf16* Bkl = (bf16*)(L + 5120);   // [256][40]
  bf16* Pl = (bf16*)L;             // [64][264] (reuse after stage-1)
  bf16* Bw2 = (bf16*)(L + 33792);  // [2][64][136]
  int t = threadIdx.x, wv = t >> 6, lane = t & 63;
  int qd = lane >> 4, lm = lane & 15;
  long bz = blockIdx.z;
  long m0 = (long)blockIdx.x * 64;
  const bf16* qA = qb + bz * (4096L * 64);
  const bf16* klA = klb + bz * (256L * 64);
  const bf16* WtA = Wt + bz * 16384;

  f32x4 a1[16];
#pragma unroll
  for (int j = 0; j < 16; ++j) a1[j] = (f32x4)0.0f;
  for (int k0 = 0; k0 < 64; k0 += 32) {
    stageA<64, 0>(qA, 64, m0, k0, Aq, t);
    stageA<256, 0>(klA, 64, 0, k0, Bkl, t);
    __syncthreads();
    bf16x8 af = *(const bf16x8*)(Aq + (wv * 16 + lm) * 40 + qd * 8);
#pragma unroll
    for (int j = 0; j < 16; ++j) {
      bf16x8 bf = *(const bf16x8*)(Bkl + (j * 16 + lm) * 40 + qd * 8);
      a1[j] = mfma16(af, bf, a1[j]);
    }
    __syncthreads();
  }

  // T14 (correct placement): issue Wt loads now — no barrier until the
  // pre-MFMA one, so they drain under the softmax's VALU work.
  bf16x8 wreg[8];
#pragma unroll
  for (int c = 0; c < 8; ++c) {
    int idx = t + 256 * c;
    int r = idx >> 5, kc = (idx & 31) * 8;
    wreg[c] = *(const bf16x8*)(WtA + r * 256 + kc);
  }

  float rs[4];
#pragma unroll
  for (int r = 0; r < 4; ++r) {
    int rowl = wv * 16 + qd * 4 + r;
    float ev[16];
    float s = 0.f;
#pragma unroll
    for (int j = 0; j < 16; ++j) { ev[j] = __expf(a1[j][r]); s += ev[j]; }
    s += __shfl_xor(s, 1); s += __shfl_xor(s, 2);
    s += __shfl_xor(s, 4); s += __shfl_xor(s, 8);
    rs[r] = s;
#pragma unroll
    for (int j = 0; j < 16; ++j) {
      float other = __shfl_xor(ev[j], 1);
      if ((lm & 1) == 0) {
        unsigned int w = f2bu(ev[j]) | ((unsigned)f2bu(other) << 16);
        *(unsigned int*)(Pl + rowl * 264 + j * 16 + lm) = w;
      }
    }
  }
  // write Wt registers to resident LDS (split into two 128-k chunks)
#pragma unroll
  for (int c = 0; c < 8; ++c) {
    int idx = t + 256 * c;
    int r = idx >> 5, kc = (idx & 31) * 8;
    int ch = kc >> 7, kk = kc & 127;
    *(bf16x8*)(Bw2 + ch * 8704 + r * 136 + kk) = wreg[c];
  }
  __syncthreads();
  f32x4 a2[4];
#pragma unroll
  for (int j = 0; j < 4; ++j) a2[j] = (f32x4)0.0f;
#pragma unroll
  for (int ch = 0; ch < 2; ++ch)
#pragma unroll
    for (int k0 = 0; k0 < 128; k0 += 32) {
      bf16x8 af = *(const bf16x8*)(Pl + (wv * 16 + lm) * 264 + ch * 128 + k0 + qd * 8);
#pragma unroll
      for (int j = 0; j < 4; ++j) {
        bf16x8 bf = *(const bf16x8*)(Bw2 + ch * 8704 + (j * 16 + lm) * 136 + k0 + qd * 8);
        a2[j] = mfma16(af, bf, a2[j]);
      }
    }
#pragma unroll
  for (int j = 0; j < 4; ++j)
#pragma unroll
    for (int r = 0; r < 4; ++r) {
      long grow = m0 + wv * 16 + qd * 4 + r;
      long col = j * 16 + lm;
      oh[(bz * 4096 + grow) * 64 + col] = (bf16)(a2[j][r] / rs[r]);
    }
}

// depthwise conv residual
__global__ __launch_bounds__(256) void k_conv2(const bf16* __restrict__ v,
                                               const float* __restrict__ kern,
                                               bf16* __restrict__ oh) {
  __shared__ __align__(16) bf16 Vs[96 * 72];
  int bx = blockIdx.x;
  int bh = bx >> 6;
  int i0 = (bx & 63) * 64;
  int t = threadIdx.x;
  const bf16* vsrc = v + (long)bh * 262144;
#pragma unroll
  for (int c = 0; c < 3; ++c) {
    int idx = t + 256 * c;
    int r = idx >> 3, dc = (idx & 7) * 8;
    int grow = i0 + r - 16;
    bf16x8 val = (bf16x8)(bf16)0.0f;
    if (grow >= 0 && grow < 4096) val = *(const bf16x8*)(vsrc + (long)grow * 64 + dc);
    *(bf16x8*)(Vs + r * 72 + dc) = val;
  }
  __syncthreads();
  int dg = t & 15, rg = t >> 4;
  const float* kc = kern + (bh & 7) * 33;
  float acc[4][4] = {};
#pragma unroll
  for (int rr = 0; rr < 36; ++rr) {
    bf16x4 xv = *(const bf16x4*)(Vs + (rg * 4 + rr) * 72 + dg * 4);
    float x0 = (float)xv[0], x1 = (float)xv[1], x2 = (float)xv[2], x3 = (float)xv[3];
#pragma unroll
    for (int r = 0; r < 4; ++r) {
      int u = rr - r;
      if (u >= 0 && u < 33) {
        float kw = kc[u];
        acc[r][0] = fmaf(kw, x0, acc[r][0]);
        acc[r][1] = fmaf(kw, x1, acc[r][1]);
        acc[r][2] = fmaf(kw, x2, acc[r][2]);
        acc[r][3] = fmaf(kw, x3, acc[r][3]);
      }
    }
  }
  long base = ((long)bh * 4096 + i0 + rg * 4) * 64 + dg * 4;
#pragma unroll
  for (int r = 0; r < 4; ++r) {
    bf16x4 o = *(const bf16x4*)(oh + base + r * 64);
    bf16x4 w;
#pragma unroll
    for (int c = 0; c < 4; ++c) w[c] = (bf16)(acc[r][c] + (float)o[c]);
    *(bf16x4*)(oh + base + r * 64) = w;
  }
}

// ---------------- host ----------------
extern "C" void kernel_launch(void* const* d_in, const int* in_sizes, int n_in,
                              void* d_out, int out_size, void* d_ws, size_t ws_size,
                              hipStream_t stream) {
  const float* x     = (const float*)d_in[0];
  const float* w_qkv = (const float*)d_in[1];
  const float* w_out = (const float*)d_in[2];
  const float* b_out = (const float*)d_in[3];
  const float* res_k = (const float*)d_in[4];

  char* w = (char*)d_ws;
  bf16* qb  = (bf16*)(w);
  bf16* kb  = (bf16*)(w + 16777216);
  bf16* vb  = (bf16*)(w + 33554432);
  bf16* qlh = (bf16*)(w + 50331648);
  bf16* qll = (bf16*)(w + 51380224);
  bf16* klh = (bf16*)(w + 52428800);
  bf16* kll = (bf16*)(w + 53477376);
  bf16* A2h = (bf16*)(w + 54525952);
  bf16* A2l = (bf16*)(w + 58720256);
  bf16* zAh = (bf16*)(w + 62914560);
  bf16* zAl = (bf16*)(w + 67108864);
  bf16* zBh = (bf16*)(w + 71303168);
  bf16* zBl = (bf16*)(w + 75497472);
  bf16* yh  = (bf16*)(w + 79691776);
  bf16* yl  = (bf16*)(w + 83886080);
  bf16* wqt = (bf16*)(w + 88080384);        // [1536][512] bf16
  bf16* wot = (bf16*)(w + 89653248);        // [512][512] bf16
  bf16* y2h = (bf16*)(w + 96468992);        // y ping-pong buffer (4 MB)
  bf16* y2l = (bf16*)(w + 100663296);       // (4 MB)
  bf16* oh  = (bf16*)(w + 104857600);       // 16.8 MB bf16
  bf16* xb  = (bf16*)(w + 104857600);       // alias: xb used before oh is written
  float* a3vf = (float*)(w + 121634816);
  bf16* a3vh = (bf16*)(w + 123731968);
  bf16* a3vl = (bf16*)(w + 124780544);
  bf16* Wt   = (bf16*)(w + 125829120);
  float* rs3 = (float*)(w + 126877696);
  unsigned int* sc  = (unsigned int*)(w + 126910464);

  // prep: x cast + zeroing + weight transposes (single launch)
  k_prep<<<4352, 256, 0, stream>>>(x, xb, a3vf, rs3, sc, w_qkv, w_out, wqt, wot);

  // qkv projection: glds-staged bf16 gemm (BK=64), XCD-affine swizzle
  GP p{};
  p.A = xb; p.ldA = 512; p.B = wqt; p.ldB = 512; p.K = 512;
  p.C0 = qb; p.C1 = kb; p.C2 = vb;
  ggemm<0, EQKV, 1><<<1536, 256, 0, stream>>>(p);

  k_landmarks<<<8192, 64, 0, stream>>>(qb, kb, qlh, qll, klh, kll);

  // attn2 = softmax(ql @ kl^T), split-precision
  p = GP{};
  p.A = qlh; p.Al = qll; p.ldA = 64; p.sA = 16384;
  p.B = klh; p.Bl = kll; p.ldB = 64; p.sB = 16384; p.K = 64;
  p.C0 = A2h; p.C1 = A2l; p.sC = 65536; p.ldC = 256;
  mgemm<64, 256, 1, 0, 0, 1, EA2, 0><<<dim3(1, 4, 32), 256, 0, stream>>>(p);

  k_colsum<<<32, 256, 0, stream>>>(A2h, A2l, sc);
  k_zinit<<<dim3(4, 4, 32), 256, 0, stream>>>(A2h, A2l, sc, zAh, zAl);

  // a3v = softmax(ql @ k^T) @ v  — flash accumulation + normalize
  // 512 blocks (qt=4 x kt=4), KVBLK=128, T14 async-stage
  k_a3v<<<512, 256, 0, stream>>>(qlh, kb, vb, a3vf, rs3);
  k_a3vnorm<<<512, 256, 0, stream>>>(a3vf, rs3, a3vh, a3vl);

  // Newton-Schulz pinv: 1 init dispatch + 6 fused strip dispatches.
  // 1024 threads/block (16 waves/CU) for latency hiding.
  k_nsy0<<<256, 1024, 0, stream>>>(A2h, zAh, yh, yl);
  bf16 *zch = zAh, *zcl = zAl, *znh = zBh, *znl = zBl;
  bf16 *yih = yh, *yil = yl, *yoh = y2h, *yol = y2l;
  for (int it = 0; it < 6; ++it) {
    if (it < 3)
      k_ns4<0, 0><<<256, 1024, 0, stream>>>(A2h, A2l, yih, yil, zch, zcl, znh, znl, yoh, yol);
    else if (it == 3)
      k_ns4<0, 1><<<256, 1024, 0, stream>>>(A2h, A2l, yih, yil, zch, zcl, znh, znl, yoh, yol);
    else if (it == 4)
      k_ns4<1, 1><<<256, 1024, 0, stream>>>(A2h, A2l, yih, yil, zch, zcl, znh, znl, yoh, yol);
    else
      k_ns4<1, -1><<<256, 1024, 0, stream>>>(A2h, A2l, yih, yil, zch, zcl, znh, znl, yoh, yol);
    bf16* tmp;
    tmp = zch; zch = znh; znh = tmp;
    tmp = zcl; zcl = znl; znl = tmp;
    tmp = yih; yih = yoh; yoh = tmp;
    tmp = yil; yil = yol; yol = tmp;
  }

  // Wt = (z @ a3v)^T
  p = GP{};
  p.A = zch; p.Al = zcl; p.ldA = 256; p.sA = 65536;
  p.B = a3vh; p.Bl = a3vl; p.ldB = 64; p.sB = 16384; p.K = 256;
  p.C0 = Wt;
  mgemm<64, 64, 2, 0, 1, 1, EWT, 0><<<dim3(1, 4, 32), 256, 0, stream>>>(p);

  // oh = softmax(q @ kl^T) @ W (fused, T14 Wt prefetch after stage-1), bf16 out
  k_attn1w<<<dim3(64, 1, 32), 256, 0, stream>>>(qb, klh, Wt, oh);

  // += depthwise conv residual
  k_conv2<<<2048, 256, 0, stream>>>(vb, res_k, oh);

  // out = gather(oh bf16) @ w_out + bias, glds-staged (BK=64), XCD-affine
  p = GP{};
  p.A = oh; p.ldA = 64; p.B = wot; p.ldB = 512; p.K = 512;
  p.C0 = d_out; p.bias = b_out;
  ggemm<3, EBIAS, 2><<<512, 256, 0, stream>>>(p);
}

// Round 14
// 419.495 us; speedup vs baseline: 1.0185x; 1.0178x over previous
//
#include <hip/hip_runtime.h>

// ---------------- problem constants ----------------
#define Nq   4096
#define DHq  64
#define Mq   256
#define BHq  32

using bf16 = __bf16;
using bf16x8 = __bf16 __attribute__((ext_vector_type(8)));
using bf16x4 = __bf16 __attribute__((ext_vector_type(4)));
using f32x4 = float __attribute__((ext_vector_type(4)));

__device__ __forceinline__ f32x4 mfma16(bf16x8 a, bf16x8 b, f32x4 c) {
  return __builtin_amdgcn_mfma_f32_16x16x32_bf16(a, b, c, 0, 0, 0);
}
__device__ __forceinline__ unsigned short f2bu(float f) {
  bf16 b = (bf16)f;
  return __builtin_bit_cast(unsigned short, b);
}
__device__ __forceinline__ void split_store(bf16* h, bf16* l, long idx, float v) {
  bf16 hi = (bf16)v;
  h[idx] = hi;
  l[idx] = (bf16)(v - (float)hi);
}

// async global->LDS, 16B per lane; LDS dest = wave-uniform base + lane*16
typedef const __attribute__((address_space(1))) void* gas_t;
typedef __attribute__((address_space(3))) void* las_t;
__device__ __forceinline__ void glds16(const bf16* g, bf16* l) {
  __builtin_amdgcn_global_load_lds((gas_t)g, (las_t)l, 16, 0, 0);
}

// Stage a ROWS x 32 bf16 tile into LDS, row stride 40 bf16 (80 B).
// SRC: 0 = bf16 row-major, 1 = f32 row-major
template<int ROWS, int SRC>
__device__ __forceinline__ void stageA(const void* src, long ld, long row0, int k0,
                                       bf16* dst, int t) {
#pragma unroll
  for (int c = 0; c < ROWS / 64; ++c) {
    int idx = t + 256 * c;
    int r = idx >> 2;
    int kc = (idx & 3) << 3;
    bf16x8 val;
    if constexpr (SRC == 0) {
      val = *(const bf16x8*)((const bf16*)src + (row0 + r) * ld + k0 + kc);
    } else {
      const float* s = (const float*)src + (row0 + r) * ld + k0 + kc;
      float4 a = *(const float4*)s;
      float4 b = *(const float4*)(s + 4);
      val[0]=(bf16)a.x; val[1]=(bf16)a.y; val[2]=(bf16)a.z; val[3]=(bf16)a.w;
      val[4]=(bf16)b.x; val[5]=(bf16)b.y; val[6]=(bf16)b.z; val[7]=(bf16)b.w;
    }
    *(bf16x8*)(dst + r * 40 + kc) = val;
  }
}

// Stage 32 x COLS tile of row-major [K][N] B into word-LDS [COLS][20 words].
template<int COLS, bool F32>
__device__ __forceinline__ void stageBN(const void* src, long ld, long n0, int k0,
                                        unsigned int* dst, int t) {
  int kp = t >> 4;
  int nb = (t & 15) << 2;
#pragma unroll
  for (int g = 0; g < COLS / 64; ++g) {
    int n = nb + (g << 6);
    unsigned int w0, w1, w2, w3;
    if constexpr (F32) {
      const float* s0 = (const float*)src + (long)(k0 + 2 * kp) * ld + n0 + n;
      const float* s1 = s0 + ld;
      float4 a = *(const float4*)s0;
      float4 b = *(const float4*)s1;
      w0 = f2bu(a.x) | ((unsigned)f2bu(b.x) << 16);
      w1 = f2bu(a.y) | ((unsigned)f2bu(b.y) << 16);
      w2 = f2bu(a.z) | ((unsigned)f2bu(b.z) << 16);
      w3 = f2bu(a.w) | ((unsigned)f2bu(b.w) << 16);
    } else {
      const unsigned short* s0 = (const unsigned short*)src + (long)(k0 + 2 * kp) * ld + n0 + n;
      const unsigned short* s1 = s0 + ld;
      ushort4 a = *(const ushort4*)s0;
      ushort4 b = *(const ushort4*)s1;
      w0 = a.x | ((unsigned)b.x << 16);
      w1 = a.y | ((unsigned)b.y << 16);
      w2 = a.z | ((unsigned)b.z << 16);
      w3 = a.w | ((unsigned)b.w << 16);
    }
    dst[(n + 0) * 20 + kp] = w0;
    dst[(n + 1) * 20 + kp] = w1;
    dst[(n + 2) * 20 + kp] = w2;
    dst[(n + 3) * 20 + kp] = w3;
  }
}

#define EQKV 0
#define EA2 1
#define EWT 8
#define EBIAS 9

struct GP {
  const void* A; const void* Al;
  const void* B; const void* Bl;
  long ldA, ldB, sA, sB;
  int K;
  void* C0; void* C1; void* C2;
  long sC, ldC;
  const void* x0; const void* x1;
  const float* bias;
};

// ---------------- mgemm (kept for attn2 / Wt small gemms) ----------------
template<int BM, int BN, int WX, int ASRC, int BMODE, int SPLIT, int EPI, int SWZ>
__global__ __launch_bounds__(256, 2) void mgemm(GP p) {
  constexpr int WY = 4 / WX;
  constexpr int TM = BM / WY, TN = BN / WX;
  constexpr int IT = TM / 16, JT = TN / 16;
  constexpr int AB = (SPLIT ? 2 : 1) * BM * 80;
  constexpr int BB = (SPLIT ? 2 : 1) * BN * 80;
  __shared__ __align__(16) char Lbuf[AB + BB];
  bf16* AsL = (bf16*)Lbuf;
  unsigned int* BsL = (unsigned int*)(Lbuf + AB);
  int t = threadIdx.x;
  int wv = t >> 6, lane = t & 63;
  int wy = wv / WX, wx = wv % WX;
  int qd = lane >> 4, lm = lane & 15;
  long bz = blockIdx.z, m0 = (long)blockIdx.y * BM, n0 = (long)blockIdx.x * BN;

  const void* Ap = (const bf16*)p.A + bz * p.sA;
  const void* Alp = nullptr;
  if constexpr (SPLIT) Alp = (const bf16*)p.Al + bz * p.sA;
  const void* Bp = (const bf16*)p.B + bz * p.sB;
  const void* Blp = nullptr;
  if constexpr (SPLIT) Blp = (const bf16*)p.Bl + bz * p.sB;

  f32x4 acc[IT][JT];
#pragma unroll
  for (int i = 0; i < IT; ++i)
#pragma unroll
    for (int j = 0; j < JT; ++j) acc[i][j] = (f32x4)0.0f;

  for (int k0 = 0; k0 < p.K; k0 += 32) {
    stageA<BM, ASRC>(Ap, p.ldA, m0, k0, AsL, t);
    if constexpr (SPLIT) stageA<BM, 0>(Alp, p.ldA, m0, k0, AsL + BM * 40, t);
    if constexpr (BMODE == 0) {
      stageA<BN, 0>(Bp, p.ldB, n0, k0, (bf16*)BsL, t);
      if constexpr (SPLIT) stageA<BN, 0>(Blp, p.ldB, n0, k0, (bf16*)BsL + BN * 40, t);
    } else {
      stageBN<BN, false>(Bp, p.ldB, n0, k0, BsL, t);
      if constexpr (SPLIT) stageBN<BN, false>(Blp, p.ldB, n0, k0, BsL + BN * 20, t);
    }
    __syncthreads();
    bf16x8 af[IT], afl[IT];
#pragma unroll
    for (int i = 0; i < IT; ++i) {
      int m = wy * TM + i * 16 + lm;
      af[i] = *(const bf16x8*)(AsL + m * 40 + qd * 8);
      if constexpr (SPLIT) afl[i] = *(const bf16x8*)(AsL + BM * 40 + m * 40 + qd * 8);
    }
#pragma unroll
    for (int j = 0; j < JT; ++j) {
      int n = wx * TN + j * 16 + lm;
      bf16x8 bf, bfl;
      if constexpr (BMODE == 0) {
        bf = *(const bf16x8*)((const bf16*)BsL + n * 40 + qd * 8);
        if constexpr (SPLIT) bfl = *(const bf16x8*)((const bf16*)BsL + BN * 40 + n * 40 + qd * 8);
      } else {
        bf = *(const bf16x8*)((const bf16*)(BsL + n * 20 + qd * 4));
        if constexpr (SPLIT) bfl = *(const bf16x8*)((const bf16*)(BsL + BN * 20 + n * 20 + qd * 4));
      }
#pragma unroll
      for (int i = 0; i < IT; ++i) {
        acc[i][j] = mfma16(af[i], bf, acc[i][j]);
        if constexpr (SPLIT) {
          acc[i][j] = mfma16(af[i], bfl, acc[i][j]);
          acc[i][j] = mfma16(afl[i], bf, acc[i][j]);
        }
      }
    }
    __syncthreads();
  }

  if constexpr (EPI == EA2) {
#pragma unroll
    for (int r = 0; r < 4; ++r) {
      long row = m0 + wy * TM + qd * 4 + r;
      float e[JT];
      float s = 0.f;
#pragma unroll
      for (int j = 0; j < JT; ++j) { e[j] = __expf(acc[0][j][r]); s += e[j]; }
      s += __shfl_xor(s, 1); s += __shfl_xor(s, 2);
      s += __shfl_xor(s, 4); s += __shfl_xor(s, 8);
      float inv = 1.0f / s;
#pragma unroll
      for (int j = 0; j < JT; ++j) {
        long col = n0 + j * 16 + lm;
        split_store((bf16*)p.C0, (bf16*)p.C1, bz * p.sC + row * p.ldC + col, e[j] * inv);
      }
    }
  } else {
#pragma unroll
    for (int i = 0; i < IT; ++i)
#pragma unroll
      for (int j = 0; j < JT; ++j)
#pragma unroll
        for (int r = 0; r < 4; ++r) {
          long row = m0 + wy * TM + i * 16 + qd * 4 + r;
          long col = n0 + wx * TN + j * 16 + lm;
          float v = acc[i][j][r];
          if constexpr (EPI == EWT) {
            ((bf16*)p.C0)[bz * 16384 + col * 256 + row] = (bf16)v;
          }
        }
  }
}

// ---------------- glds-staged 128x128 gemm (QKV + out-proj, BK=64) ----------------
template<int ASRC, int EPI, int SWZ>
__global__ __launch_bounds__(256, 3) void ggemm(GP p) {
  __shared__ __align__(64) bf16 AsL[2][128 * 32];
  __shared__ __align__(64) bf16 BsL[2][128 * 32];
  int t = threadIdx.x, wv = t >> 6, lane = t & 63;
  int wy = wv >> 1, wx = wv & 1;
  int qd = lane >> 4, lm = lane & 15;
  long m0, n0;
  if constexpr (SWZ == 1) {
    int b = blockIdx.x, xcd = b & 7, s = b >> 3;
    m0 = (long)(xcd * 16 + s / 12) * 128; n0 = (long)(s % 12) * 128;
  } else {
    int b = blockIdx.x, xcd = b & 7, s = b >> 3;
    m0 = (long)(xcd * 16 + (s >> 2)) * 128; n0 = (long)(s & 3) * 128;
  }
  const bf16* A = (const bf16*)p.A;
  const bf16* B = (const bf16*)p.B;

  f32x4 acc[4][4];
#pragma unroll
  for (int i = 0; i < 4; ++i)
#pragma unroll
    for (int j = 0; j < 4; ++j) acc[i][j] = (f32x4)0.0f;

  int rsub = lane >> 2;           // 0..15 row within 16-row group
  int kc = (lane & 3) << 3;       // 0,8,16,24 bf16 col offset
  for (int k0 = 0; k0 < p.K; k0 += 64) {
#pragma unroll
    for (int half = 0; half < 2; ++half) {
      int kk = k0 + half * 32;
#pragma unroll
      for (int e = 0; e < 2; ++e) {
        int br = wv * 32 + e * 16;          // wave-uniform base row
        long rA = m0 + br + rsub;
        const bf16* gA;
        if constexpr (ASRC == 0) {
          gA = A + rA * p.ldA + kk + kc;
        } else {
          long bb = rA >> 12, ii = rA & 4095;
          int k = kk + kc;
          long h = k >> 6, d = k & 63;
          gA = A + (((bb * 8 + h) * 4096 + ii) * 64 + d);
        }
        glds16(gA, AsL[half] + br * 32);
        const bf16* gB = B + (n0 + br + rsub) * p.ldB + kk + kc;
        glds16(gB, BsL[half] + br * 32);
      }
    }
    __syncthreads();
#pragma unroll
    for (int half = 0; half < 2; ++half) {
      bf16x8 af[4];
#pragma unroll
      for (int i = 0; i < 4; ++i)
        af[i] = *(const bf16x8*)(AsL[half] + (wy * 64 + i * 16 + lm) * 32 + qd * 8);
#pragma unroll
      for (int j = 0; j < 4; ++j) {
        bf16x8 bv = *(const bf16x8*)(BsL[half] + (wx * 64 + j * 16 + lm) * 32 + qd * 8);
#pragma unroll
        for (int i = 0; i < 4; ++i) acc[i][j] = mfma16(af[i], bv, acc[i][j]);
      }
    }
    __syncthreads();
  }

#pragma unroll
  for (int i = 0; i < 4; ++i)
#pragma unroll
    for (int j = 0; j < 4; ++j)
#pragma unroll
      for (int r = 0; r < 4; ++r) {
        long row = m0 + wy * 64 + i * 16 + qd * 4 + r;
        long col = n0 + wx * 64 + j * 16 + lm;
        float v = acc[i][j][r];
        if constexpr (EPI == EQKV) {
          int part = (int)(col >> 9);
          long h = (col >> 6) & 7, d = col & 63;
          long bb = row >> 12, ii = row & 4095;
          float scv = part == 0 ? 0.125f : 1.0f;
          bf16* dst = part == 0 ? (bf16*)p.C0 : (part == 1 ? (bf16*)p.C1 : (bf16*)p.C2);
          dst[((bb * 8 + h) * 4096 + ii) * 64 + d] = (bf16)(v * scv);
        } else {
          ((float*)p.C0)[row * 512 + col] = v + p.bias[col];
        }
      }
}

// ---------------- fused prep: x->bf16 cast + zeroing + weight transposes ------
__global__ __launch_bounds__(256) void k_prep(const float* __restrict__ x,
                                              bf16* __restrict__ xb,
                                              float* a3vf, float* rs3, unsigned int* sc,
                                              const float* __restrict__ wq,
                                              const float* __restrict__ wo,
                                              bf16* __restrict__ wqt,
                                              bf16* __restrict__ wot) {
  __shared__ float T[64][65];
  int bid = blockIdx.x, t = threadIdx.x;
  if (bid < 4096) {
    long i = (long)bid * 256 + t;
    long e = i * 8;
    float4 a = *(const float4*)(x + e);
    float4 b = *(const float4*)(x + e + 4);
    bf16x8 v;
    v[0]=(bf16)a.x; v[1]=(bf16)a.y; v[2]=(bf16)a.z; v[3]=(bf16)a.w;
    v[4]=(bf16)b.x; v[5]=(bf16)b.y; v[6]=(bf16)b.z; v[7]=(bf16)b.w;
    *(bf16x8*)(xb + e) = v;
    if (i < 524288) a3vf[i] = 0.f;
    if (i < 8192) rs3[i] = 0.f;
    if (i == 0) sc[0] = 0u;
  } else {
    int w = bid - 4096;           // 0..255
    int bx = w >> 3, ti = w & 7;
    const float* src; bf16* dst; int N, tj;
    if (bx < 24) { src = wq; dst = wqt; N = 1536; tj = bx; }
    else         { src = wo; dst = wot; N = 512;  tj = bx - 24; }
    int c = t & 63, r0 = t >> 6;
#pragma unroll
    for (int rr = 0; rr < 16; ++rr) {
      int r = r0 * 16 + rr;
      T[r][c] = src[(long)(ti * 64 + r) * N + tj * 64 + c];
    }
    __syncthreads();
#pragma unroll
    for (int rr = 0; rr < 16; ++rr) {
      int n = r0 * 16 + rr;
      dst[(long)(tj * 64 + n) * 512 + ti * 64 + c] = (bf16)T[c][n];
    }
  }
}

// ---------------- strip-resident Newton-Schulz (32-col strips, 256 blocks) ----
// 1024 threads/block (16 waves/CU); verified round 8.
#define SBW 132

__device__ __forceinline__ void stageBS32(const bf16* src, long n0, int k0,
                                          unsigned int* dst, int t) {
  int kp = t >> 3, nb = (t & 7) << 2;
  const unsigned short* s0 = (const unsigned short*)src + (long)(k0 + 2 * kp) * 256 + n0 + nb;
  const unsigned short* s1 = s0 + 256;
  ushort4 a = *(const ushort4*)s0;
  ushort4 b = *(const ushort4*)s1;
  int wb = (k0 >> 1) + kp;
  dst[(nb + 0) * SBW + wb] = a.x | ((unsigned)b.x << 16);
  dst[(nb + 1) * SBW + wb] = a.y | ((unsigned)b.y << 16);
  dst[(nb + 2) * SBW + wb] = a.z | ((unsigned)b.z << 16);
  dst[(nb + 3) * SBW + wb] = a.w | ((unsigned)b.w << 16);
}

// C rows [w*16, w*16+16) x 32 cols = A-rows(global) @ B_strip(LDS). 16 waves.
template<int SPLIT>
__device__ __forceinline__ void sgemm32(const bf16* Ah, const bf16* Al,
                                        const unsigned int* Bs, const unsigned int* Bsl,
                                        int w, int lane, f32x4 acc[2]) {
  int qd = lane >> 4, lm = lane & 15;
  acc[0] = (f32x4)0.0f;
  acc[1] = (f32x4)0.0f;
#pragma unroll 2
  for (int k0 = 0; k0 < 256; k0 += 32) {
    long m = w * 16 + lm;
    bf16x8 af = *(const bf16x8*)(Ah + m * 256 + k0 + qd * 8);
    bf16x8 afl;
    if constexpr (SPLIT) afl = *(const bf16x8*)(Al + m * 256 + k0 + qd * 8);
#pragma unroll
    for (int j = 0; j < 2; ++j) {
      bf16x8 bv = *(const bf16x8*)((const bf16*)(Bs + (j * 16 + lm) * SBW + (k0 >> 1) + qd * 4));
      acc[j] = mfma16(af, bv, acc[j]);
      if constexpr (SPLIT) {
        bf16x8 bl = *(const bf16x8*)((const bf16*)(Bsl + (j * 16 + lm) * SBW + (k0 >> 1) + qd * 4));
        acc[j] = mfma16(af, bl, acc[j]);
        acc[j] = mfma16(afl, bv, acc[j]);
      }
    }
  }
}

// pack 4 rows (R0..R0+3) of column col into transposed strip LDS (h, and l residual)
template<int HASL>
__device__ __forceinline__ void packStrip(unsigned int* Sh, unsigned int* Sl,
                                          int col, int R0, const float* v) {
  unsigned int* Wp = Sh + col * SBW + (R0 >> 1);
  Wp[0] = f2bu(v[0]) | ((unsigned)f2bu(v[1]) << 16);
  Wp[1] = f2bu(v[2]) | ((unsigned)f2bu(v[3]) << 16);
  if constexpr (HASL) {
    unsigned int* Wq = Sl + col * SBW + (R0 >> 1);
    Wq[0] = f2bu(v[0] - (float)(bf16)v[0]) | ((unsigned)f2bu(v[1] - (float)(bf16)v[1]) << 16);
    Wq[1] = f2bu(v[2] - (float)(bf16)v[2]) | ((unsigned)f2bu(v[3] - (float)(bf16)v[3]) << 16);
  }
}

// XCD-affine block -> (bh, strip) mapping
__device__ __forceinline__ void nsmap(int b, long& bh, long& js) {
  int xcd = b & 7, s = b >> 3;
  bh = xcd * 4 + (s >> 3);
  js = (long)(s & 7) * 32;
}

// y0 = A2 @ z0 (non-split inputs, split-stored output)
__global__ __launch_bounds__(1024) void k_nsy0(const bf16* __restrict__ A2h,
                                               const bf16* __restrict__ zh,
                                               bf16* __restrict__ yh, bf16* __restrict__ yl) {
  __shared__ __align__(16) unsigned int Bs[32 * SBW];
  int b = blockIdx.x, t = threadIdx.x;
  long bh, js;
  nsmap(b, bh, js);
  const bf16* Ah = A2h + bh * 65536;
  const bf16* Bz = zh + bh * 65536;
  if (t < 128) {
#pragma unroll
    for (int k0 = 0; k0 < 256; k0 += 32) stageBS32(Bz, js, k0, Bs, t);
  }
  __syncthreads();
  int w = t >> 6, lane = t & 63, qd = lane >> 4, lm = lane & 15;
  f32x4 acc[2];
  sgemm32<0>(Ah, Ah, Bs, Bs, w, lane, acc);
  bf16* yhb = yh + bh * 65536;
  bf16* ylb = yl + bh * 65536;
#pragma unroll
  for (int j = 0; j < 2; ++j)
#pragma unroll
    for (int r = 0; r < 4; ++r) {
      long row = w * 16 + qd * 4 + r;
      long col = js + j * 16 + lm;
      split_store(yhb, ylb, row * 256 + col, acc[j][r]);
    }
}

// One NS iteration for one 32-col strip (see round-8 comments).
template<int SPLIT, int YS>
__global__ __launch_bounds__(1024) void k_ns4(
    const bf16* __restrict__ A2h, const bf16* __restrict__ A2l,
    const bf16* __restrict__ yih, const bf16* __restrict__ yil,
    const bf16* __restrict__ zh_, const bf16* __restrict__ zl_,
    bf16* __restrict__ znh_, bf16* __restrict__ znl_,
    bf16* __restrict__ yoh_, bf16* __restrict__ yol_) {
  constexpr int P0 = SPLIT ? 2 : 1;
  constexpr int P1 = (SPLIT || YS == 1) ? 2 : 1;
  __shared__ __align__(16) unsigned int S0[P0][32 * SBW];
  __shared__ __align__(16) unsigned int S1[P1][32 * SBW];
  int b = blockIdx.x, t = threadIdx.x;
  long bh, js;
  nsmap(b, bh, js);
  const bf16* yH = yih + bh * 65536;
  const bf16* yL = yil + bh * 65536;
  const bf16* zH = zh_ + bh * 65536;
  const bf16* zL = zl_ + bh * 65536;
  const bf16* aH = A2h + bh * 65536;
  const bf16* aL = A2l + bh * 65536;
  unsigned int* S0l = S0[P0 - 1];
  unsigned int* S1l = S1[P1 - 1];
  if (t < 128) {
#pragma unroll
    for (int k0 = 0; k0 < 256; k0 += 32) {
      stageBS32(yH, js, k0, S0[0], t);
      if constexpr (SPLIT) stageBS32(yL, js, k0, S0l, t);
    }
  }
  __syncthreads();
  int w = t >> 6, lane = t & 63, qd = lane >> 4, lm = lane & 15;
  f32x4 acc[2];

  // gemm1: bb = 15I - 7y + y @ y_strip -> S1
  sgemm32<SPLIT>(yH, yL, S0[0], S0l, w, lane, acc);
#pragma unroll
  for (int j = 0; j < 2; ++j) {
    int R0 = w * 16 + qd * 4;
    int col = j * 16 + lm;
    float v[4];
#pragma unroll
    for (int r = 0; r < 4; ++r) {
      long row = R0 + r;
      long ix = row * 256 + js + col;
      float yv = (float)yH[ix] + (float)yL[ix];
      v[r] = ((row == js + col) ? 15.0f : 0.0f) - 7.0f * yv + acc[j][r];
    }
    packStrip<SPLIT>(S1[0], S1l, col, R0, v);
  }
  __syncthreads();

  // gemm2: cc = 13I - y @ bb_strip -> S0
  sgemm32<SPLIT>(yH, yL, S1[0], S1l, w, lane, acc);
#pragma unroll
  for (int j = 0; j < 2; ++j) {
    int R0 = w * 16 + qd * 4;
    int col = j * 16 + lm;
    float v[4];
#pragma unroll
    for (int r = 0; r < 4; ++r)
      v[r] = (((long)(R0 + r) == js + col) ? 13.0f : 0.0f) - acc[j][r];
    packStrip<SPLIT>(S0[0], S0l, col, R0, v);
  }
  __syncthreads();

  // gemm3: zn = 0.25 * z @ cc_strip -> global split [+ pack S1]
  sgemm32<SPLIT>(zH, zL, S0[0], S0l, w, lane, acc);
  bf16* zoh = znh_ + bh * 65536;
  bf16* zol = znl_ + bh * 65536;
#pragma unroll
  for (int j = 0; j < 2; ++j) {
    int R0 = w * 16 + qd * 4;
    int col = j * 16 + lm;
    float v[4];
#pragma unroll
    for (int r = 0; r < 4; ++r) {
      v[r] = 0.25f * acc[j][r];
      split_store(zoh, zol, (long)(R0 + r) * 256 + js + col, v[r]);
    }
    if constexpr (YS >= 0) packStrip<(YS == 1) ? 1 : 0>(S1[0], S1l, col, R0, v);
  }

  // gemm4: y' = A2 @ zn_strip -> global split
  if constexpr (YS >= 0) {
    __syncthreads();
    sgemm32<(YS == 1) ? 1 : 0>(aH, aL, S1[0], S1l, w, lane, acc);
    bf16* yoh = yoh_ + bh * 65536;
    bf16* yol = yol_ + bh * 65536;
#pragma unroll
    for (int j = 0; j < 2; ++j)
#pragma unroll
      for (int r = 0; r < 4; ++r) {
        long row = w * 16 + qd * 4 + r;
        long col = js + j * 16 + lm;
        split_store(yoh, yol, row * 256 + col, acc[j][r]);
      }
  }
}

// ---------------- flash a3v (kt=4, 512 blocks, KVBLK=128, T14) ----------------
// Verified round 11: 8 iterations x 3 barriers, 32 MFMA between barrier pairs.
__device__ __forceinline__ void loadKrow4(const bf16* ks_, int t, bf16x8 kr[4]) {
#pragma unroll
  for (int c = 0; c < 4; ++c) {
    int idx = t + 256 * c;
    int r = idx >> 3, dc = (idx & 7) * 8;
    kr[c] = *(const bf16x8*)(ks_ + r * 64 + dc);
  }
}
__device__ __forceinline__ void writeKrow4(bf16* kS, int t, const bf16x8 kr[4]) {
#pragma unroll
  for (int c = 0; c < 4; ++c) {
    int idx = t + 256 * c;
    int r = idx >> 3, dc = (idx & 7) * 8;
    *(bf16x8*)(kS + r * 72 + dc) = kr[c];
  }
}
__device__ __forceinline__ void loadVhalf(const bf16* vs_, int k0, int t,
                                          ushort4& a, ushort4& b) {
  int kp = t >> 4, nb = (t & 15) << 2;
  const unsigned short* s0 = (const unsigned short*)vs_ + (long)(k0 + 2 * kp) * 64 + nb;
  a = *(const ushort4*)s0;
  b = *(const ushort4*)(s0 + 64);
}
__device__ __forceinline__ void writeVhalf(unsigned int* dst, int t, ushort4 a, ushort4 b) {
  int kp = t >> 4, nb = (t & 15) << 2;
  dst[(nb + 0) * 20 + kp] = a.x | ((unsigned)b.x << 16);
  dst[(nb + 1) * 20 + kp] = a.y | ((unsigned)b.y << 16);
  dst[(nb + 2) * 20 + kp] = a.z | ((unsigned)b.z << 16);
  dst[(nb + 3) * 20 + kp] = a.w | ((unsigned)b.w << 16);
}

__global__ __launch_bounds__(256, 2) void k_a3v(const bf16* __restrict__ qlh,
                                                const bf16* __restrict__ kb,
                                                const bf16* __restrict__ vb,
                                                float* __restrict__ a3vf,
                                                float* __restrict__ rs3) {
  __shared__ __align__(16) char L[66048];
  bf16* qlS = (bf16*)L;                           // [64][72]
  bf16* kS  = (bf16*)(L + 9216);                  // [128][72]
  bf16* PA  = (bf16*)(L + 27648);                 // [64][136]
  unsigned int* vBb = (unsigned int*)(L + 45056); // 4 x [64][20] words
  float* rsL = (float*)(L + 65536);               // [64][2]
  int b = blockIdx.x, t = threadIdx.x;
  int xcd = b & 7, s = b >> 3;
  int strip = xcd * 16 + (s >> 2);
  int qt = s & 3;
  long bz = strip >> 2;
  int kt = strip & 3;
  int wv = t >> 6, lane = t & 63, qd = lane >> 4, lm = lane & 15;
  int wy = wv >> 1, wx = wv & 1;
  const bf16* qlp = qlh + bz * 16384 + qt * 64 * 64;
#pragma unroll
  for (int c = 0; c < 2; ++c) {
    int idx = t + 256 * c;
    int r = idx >> 3, dc = (idx & 7) * 8;
    *(bf16x8*)(qlS + r * 72 + dc) = *(const bf16x8*)(qlp + r * 64 + dc);
  }
  const bf16* kb_ = kb + bz * 262144 + (long)kt * 65536;
  const bf16* vb_ = vb + bz * 262144 + (long)kt * 65536;
  f32x4 accO[2][2];
  float rsum[2][4];
#pragma unroll
  for (int i = 0; i < 2; ++i) {
#pragma unroll
    for (int j = 0; j < 2; ++j) accO[i][j] = (f32x4)0.0f;
#pragma unroll
    for (int r = 0; r < 4; ++r) rsum[i][r] = 0.f;
  }
  // prefetch tt=0 into registers (128 K rows, 128 V rows)
  bf16x8 kr[4];
  ushort4 va[4], vbq[4];
  loadKrow4(kb_, t, kr);
#pragma unroll
  for (int q = 0; q < 4; ++q) loadVhalf(vb_, q * 32, t, va[q], vbq[q]);
  for (int tt = 0; tt < 8; ++tt) {
    __syncthreads();
    writeKrow4(kS, t, kr);
#pragma unroll
    for (int q = 0; q < 4; ++q) writeVhalf(vBb + q * 1280, t, va[q], vbq[q]);
    __syncthreads();
    if (tt < 7) {   // issue next tile's loads; they complete under QK/SM/PV
      const bf16* ks2 = kb_ + (tt + 1) * 8192;
      const bf16* vs2 = vb_ + (tt + 1) * 8192;
      loadKrow4(ks2, t, kr);
#pragma unroll
      for (int q = 0; q < 4; ++q) loadVhalf(vs2, q * 32, t, va[q], vbq[q]);
    }
    f32x4 s2[2][4];
#pragma unroll
    for (int i = 0; i < 2; ++i)
#pragma unroll
      for (int j = 0; j < 4; ++j) s2[i][j] = (f32x4)0.0f;
#pragma unroll
    for (int ks = 0; ks < 2; ++ks) {
      bf16x8 af[2];
#pragma unroll
      for (int i = 0; i < 2; ++i)
        af[i] = *(const bf16x8*)(qlS + (wy * 32 + i * 16 + lm) * 72 + ks * 32 + qd * 8);
#pragma unroll
      for (int j = 0; j < 4; ++j) {
        bf16x8 bfv = *(const bf16x8*)(kS + (wx * 64 + j * 16 + lm) * 72 + ks * 32 + qd * 8);
#pragma unroll
        for (int i = 0; i < 2; ++i) s2[i][j] = mfma16(af[i], bfv, s2[i][j]);
      }
    }
#pragma unroll
    for (int i = 0; i < 2; ++i)
#pragma unroll
      for (int r = 0; r < 4; ++r) {
        int row = wy * 32 + i * 16 + qd * 4 + r;
        float cs = 0.f;
#pragma unroll
        for (int j = 0; j < 4; ++j) {
          float e = __expf(s2[i][j][r]);
          PA[row * 136 + wx * 64 + j * 16 + lm] = (bf16)e;
          cs += e;
        }
        cs += __shfl_xor(cs, 1); cs += __shfl_xor(cs, 2);
        cs += __shfl_xor(cs, 4); cs += __shfl_xor(cs, 8);
        rsum[i][r] += cs;
      }
    __syncthreads();
#pragma unroll
    for (int ks = 0; ks < 4; ++ks) {
      const unsigned int* vB = vBb + ks * 1280;
      bf16x8 af[2];
#pragma unroll
      for (int i = 0; i < 2; ++i)
        af[i] = *(const bf16x8*)(PA + (wy * 32 + i * 16 + lm) * 136 + ks * 32 + qd * 8);
#pragma unroll
      for (int j = 0; j < 2; ++j) {
        bf16x8 bfv = *(const bf16x8*)((const bf16*)(vB + (wx * 32 + j * 16 + lm) * 20) + qd * 8);
#pragma unroll
        for (int i = 0; i < 2; ++i) accO[i][j] = mfma16(af[i], bfv, accO[i][j]);
      }
    }
  }
  if (lm == 0) {
#pragma unroll
    for (int i = 0; i < 2; ++i)
#pragma unroll
      for (int r = 0; r < 4; ++r)
        rsL[(wy * 32 + i * 16 + qd * 4 + r) * 2 + wx] = rsum[i][r];
  }
  __syncthreads();
  if (t < 64) atomicAdd(&rs3[bz * 256 + qt * 64 + t], rsL[t * 2] + rsL[t * 2 + 1]);
#pragma unroll
  for (int i = 0; i < 2; ++i)
#pragma unroll
    for (int j = 0; j < 2; ++j)
#pragma unroll
      for (int r = 0; r < 4; ++r) {
        long row = bz * 256 + qt * 64 + wy * 32 + i * 16 + qd * 4 + r;
        long col = wx * 32 + j * 16 + lm;
        atomicAdd(&a3vf[row * 64 + col], accO[i][j][r]);
      }
}

__global__ void k_a3vnorm(const float* __restrict__ a3vf, const float* __restrict__ rs3,
                          bf16* __restrict__ a3vh, bf16* __restrict__ a3vl) {
  long e0 = ((long)blockIdx.x * 256 + threadIdx.x) * 4;
  float4 vv = *(const float4*)&a3vf[e0];
  float inv = 1.0f / rs3[e0 >> 6];
  split_store(a3vh, a3vl, e0 + 0, vv.x * inv);
  split_store(a3vh, a3vl, e0 + 1, vv.y * inv);
  split_store(a3vh, a3vl, e0 + 2, vv.z * inv);
  split_store(a3vh, a3vl, e0 + 3, vv.w * inv);
}

// ---------------- small kernels ----------------
__global__ void k_landmarks(const bf16* q, const bf16* k, bf16* qlh, bf16* qll,
                            bf16* klh, bf16* kll) {
  int bm = blockIdx.x;
  int bh = bm >> 8, mi = bm & 255;
  int d = threadIdx.x;
  const bf16* qp = q + ((long)bh * 4096 + mi * 16) * 64 + d;
  const bf16* kp = k + ((long)bh * 4096 + mi * 16) * 64 + d;
  float sq = 0.f, sk = 0.f;
#pragma unroll
  for (int tt = 0; tt < 16; ++tt) { sq += (float)qp[tt * 64]; sk += (float)kp[tt * 64]; }
  sq *= 0.0625f; sk *= 0.0625f;
  long o = (long)bh * 16384 + mi * 64 + d;
  split_store(qlh, qll, o, sq);
  split_store(klh, kll, o, sk);
}

__global__ __launch_bounds__(256) void k_colsum(const bf16* A2h, const bf16* A2l,
                                                unsigned int* sc) {
  int bh = blockIdx.x, j = threadIdx.x;
  const bf16* ph = A2h + (long)bh * 65536 + j;
  const bf16* pl = A2l + (long)bh * 65536 + j;
  float s = 0.f;
  for (int i = 0; i < 256; ++i) s += (float)ph[i * 256] + (float)pl[i * 256];
  __shared__ float red[256];
  red[j] = s; __syncthreads();
  for (int o = 128; o > 0; o >>= 1) {
    if (j < o) red[j] = fmaxf(red[j], red[j + o]);
    __syncthreads();
  }
  if (j == 0) atomicMax(sc, __float_as_uint(red[0]));
}

__global__ __launch_bounds__(256) void k_zinit(const bf16* A2h, const bf16* A2l,
                                               const unsigned int* sc, bf16* zh, bf16* zl) {
  __shared__ float T[64][65];
  int bh = blockIdx.z, ti = blockIdx.y, tj = blockIdx.x;
  int t = threadIdx.x;
  int c = t & 63, r0 = t >> 6;
  long base = (long)bh * 65536;
  float inv = 1.0f / __uint_as_float(sc[0]);
#pragma unroll
  for (int rr = 0; rr < 16; ++rr) {
    int r = r0 * 16 + rr;
    long idx = base + (long)(ti * 64 + r) * 256 + tj * 64 + c;
    T[r][c] = (float)A2h[idx] + (float)A2l[idx];
  }
  __syncthreads();
#pragma unroll
  for (int rr = 0; rr < 16; ++rr) {
    int jl = r0 * 16 + rr;
    float v = T[c][jl] * inv;
    long o = base + (long)(tj * 64 + jl) * 256 + ti * 64 + c;
    split_store(zh, zl, o, v);
  }
}

// fused: oh = softmax(q @ kl^T) @ W  (bf16 out), Wt [bh][64][256]
// Round-11 verified structure (38.9 KB LDS -> 4 blocks/CU; rounds 12/13's
// resident-Wt variants needed 68.6 KB -> 2 blocks/CU and were net slower).
__global__ __launch_bounds__(256, 2) void k_attn1w(const bf16* qb, const bf16* klb,
                                                   const bf16* Wt, bf16* oh) {
  __shared__ __align__(16) char L[38912];
  bf16* Aq = (bf16*)L;
  bf16* Bkl = (bf16*)(L + 5120);
  bf16* Pl = (bf16*)L;
  bf16* Bw = (bf16*)(L + 33792);
  int t = threadIdx.x, wv = t >> 6, lane = t & 63;
  int qd = lane >> 4, lm = lane & 15;
  long bz = blockIdx.z;
  long m0 = (long)blockIdx.x * 64;
  const bf16* qA = qb + bz * (4096L * 64);
  const bf16* klA = klb + bz * (256L * 64);
  const bf16* WtA = Wt + bz * 16384;

  f32x4 a1[16];
#pragma unroll
  for (int j = 0; j < 16; ++j) a1[j] = (f32x4)0.0f;
  for (int k0 = 0; k0 < 64; k0 += 32) {
    stageA<64, 0>(qA, 64, m0, k0, Aq, t);
    stageA<256, 0>(klA, 64, 0, k0, Bkl, t);
    __syncthreads();
    bf16x8 af = *(const bf16x8*)(Aq + (wv * 16 + lm) * 40 + qd * 8);
#pragma unroll
    for (int j = 0; j < 16; ++j) {
      bf16x8 bf = *(const bf16x8*)(Bkl + (j * 16 + lm) * 40 + qd * 8);
      a1[j] = mfma16(af, bf, a1[j]);
    }
    __syncthreads();
  }
  float rs[4];
#pragma unroll
  for (int r = 0; r < 4; ++r) {
    int rowl = wv * 16 + qd * 4 + r;
    float ev[16];
    float s = 0.f;
#pragma unroll
    for (int j = 0; j < 16; ++j) { ev[j] = __expf(a1[j][r]); s += ev[j]; }
    s += __shfl_xor(s, 1); s += __shfl_xor(s, 2);
    s += __shfl_xor(s, 4); s += __shfl_xor(s, 8);
    rs[r] = s;
#pragma unroll
    for (int j = 0; j < 16; ++j) {
      float other = __shfl_xor(ev[j], 1);
      if ((lm & 1) == 0) {
        unsigned int w = f2bu(ev[j]) | ((unsigned)f2bu(other) << 16);
        *(unsigned int*)(Pl + rowl * 264 + j * 16 + lm) = w;
      }
    }
  }
  f32x4 a2[4];
#pragma unroll
  for (int j = 0; j < 4; ++j) a2[j] = (f32x4)0.0f;
  for (int k0 = 0; k0 < 256; k0 += 32) {
    stageA<64, 0>(WtA, 256, 0, k0, Bw, t);
    __syncthreads();
    bf16x8 af = *(const bf16x8*)(Pl + (wv * 16 + lm) * 264 + k0 + qd * 8);
#pragma unroll
    for (int j = 0; j < 4; ++j) {
      bf16x8 bf = *(const bf16x8*)(Bw + (j * 16 + lm) * 40 + qd * 8);
      a2[j] = mfma16(af, bf, a2[j]);
    }
    __syncthreads();
  }
#pragma unroll
  for (int j = 0; j < 4; ++j)
#pragma unroll
    for (int r = 0; r < 4; ++r) {
      long grow = m0 + wv * 16 + qd * 4 + r;
      long col = j * 16 + lm;
      oh[(bz * 4096 + grow) * 64 + col] = (bf16)(a2[j][r] / rs[r]);
    }
}

// depthwise conv residual
__global__ __launch_bounds__(256) void k_conv2(const bf16* __restrict__ v,
                                               const float* __restrict__ kern,
                                               bf16* __restrict__ oh) {
  __shared__ __align__(16) bf16 Vs[96 * 72];
  int bx = blockIdx.x;
  int bh = bx >> 6;
  int i0 = (bx & 63) * 64;
  int t = threadIdx.x;
  const bf16* vsrc = v + (long)bh * 262144;
#pragma unroll
  for (int c = 0; c < 3; ++c) {
    int idx = t + 256 * c;
    int r = idx >> 3, dc = (idx & 7) * 8;
    int grow = i0 + r - 16;
    bf16x8 val = (bf16x8)(bf16)0.0f;
    if (grow >= 0 && grow < 4096) val = *(const bf16x8*)(vsrc + (long)grow * 64 + dc);
    *(bf16x8*)(Vs + r * 72 + dc) = val;
  }
  __syncthreads();
  int dg = t & 15, rg = t >> 4;
  const float* kc = kern + (bh & 7) * 33;
  float acc[4][4] = {};
#pragma unroll
  for (int rr = 0; rr < 36; ++rr) {
    bf16x4 xv = *(const bf16x4*)(Vs + (rg * 4 + rr) * 72 + dg * 4);
    float x0 = (float)xv[0], x1 = (float)xv[1], x2 = (float)xv[2], x3 = (float)xv[3];
#pragma unroll
    for (int r = 0; r < 4; ++r) {
      int u = rr - r;
      if (u >= 0 && u < 33) {
        float kw = kc[u];
        acc[r][0] = fmaf(kw, x0, acc[r][0]);
        acc[r][1] = fmaf(kw, x1, acc[r][1]);
        acc[r][2] = fmaf(kw, x2, acc[r][2]);
        acc[r][3] = fmaf(kw, x3, acc[r][3]);
      }
    }
  }
  long base = ((long)bh * 4096 + i0 + rg * 4) * 64 + dg * 4;
#pragma unroll
  for (int r = 0; r < 4; ++r) {
    bf16x4 o = *(const bf16x4*)(oh + base + r * 64);
    bf16x4 w;
#pragma unroll
    for (int c = 0; c < 4; ++c) w[c] = (bf16)(acc[r][c] + (float)o[c]);
    *(bf16x4*)(oh + base + r * 64) = w;
  }
}

// ---------------- host ----------------
extern "C" void kernel_launch(void* const* d_in, const int* in_sizes, int n_in,
                              void* d_out, int out_size, void* d_ws, size_t ws_size,
                              hipStream_t stream) {
  const float* x     = (const float*)d_in[0];
  const float* w_qkv = (const float*)d_in[1];
  const float* w_out = (const float*)d_in[2];
  const float* b_out = (const float*)d_in[3];
  const float* res_k = (const float*)d_in[4];

  char* w = (char*)d_ws;
  bf16* qb  = (bf16*)(w);
  bf16* kb  = (bf16*)(w + 16777216);
  bf16* vb  = (bf16*)(w + 33554432);
  bf16* qlh = (bf16*)(w + 50331648);
  bf16* qll = (bf16*)(w + 51380224);
  bf16* klh = (bf16*)(w + 52428800);
  bf16* kll = (bf16*)(w + 53477376);
  bf16* A2h = (bf16*)(w + 54525952);
  bf16* A2l = (bf16*)(w + 58720256);
  bf16* zAh = (bf16*)(w + 62914560);
  bf16* zAl = (bf16*)(w + 67108864);
  bf16* zBh = (bf16*)(w + 71303168);
  bf16* zBl = (bf16*)(w + 75497472);
  bf16* yh  = (bf16*)(w + 79691776);
  bf16* yl  = (bf16*)(w + 83886080);
  bf16* wqt = (bf16*)(w + 88080384);        // [1536][512] bf16
  bf16* wot = (bf16*)(w + 89653248);        // [512][512] bf16
  bf16* y2h = (bf16*)(w + 96468992);        // y ping-pong buffer (4 MB)
  bf16* y2l = (bf16*)(w + 100663296);       // (4 MB)
  bf16* oh  = (bf16*)(w + 104857600);       // 16.8 MB bf16
  bf16* xb  = (bf16*)(w + 104857600);       // alias: xb used before oh is written
  float* a3vf = (float*)(w + 121634816);
  bf16* a3vh = (bf16*)(w + 123731968);
  bf16* a3vl = (bf16*)(w + 124780544);
  bf16* Wt   = (bf16*)(w + 125829120);
  float* rs3 = (float*)(w + 126877696);
  unsigned int* sc  = (unsigned int*)(w + 126910464);

  // prep: x cast + zeroing + weight transposes (single launch)
  k_prep<<<4352, 256, 0, stream>>>(x, xb, a3vf, rs3, sc, w_qkv, w_out, wqt, wot);

  // qkv projection: glds-staged bf16 gemm (BK=64), XCD-affine swizzle
  GP p{};
  p.A = xb; p.ldA = 512; p.B = wqt; p.ldB = 512; p.K = 512;
  p.C0 = qb; p.C1 = kb; p.C2 = vb;
  ggemm<0, EQKV, 1><<<1536, 256, 0, stream>>>(p);

  k_landmarks<<<8192, 64, 0, stream>>>(qb, kb, qlh, qll, klh, kll);

  // attn2 = softmax(ql @ kl^T), split-precision
  p = GP{};
  p.A = qlh; p.Al = qll; p.ldA = 64; p.sA = 16384;
  p.B = klh; p.Bl = kll; p.ldB = 64; p.sB = 16384; p.K = 64;
  p.C0 = A2h; p.C1 = A2l; p.sC = 65536; p.ldC = 256;
  mgemm<64, 256, 1, 0, 0, 1, EA2, 0><<<dim3(1, 4, 32), 256, 0, stream>>>(p);

  k_colsum<<<32, 256, 0, stream>>>(A2h, A2l, sc);
  k_zinit<<<dim3(4, 4, 32), 256, 0, stream>>>(A2h, A2l, sc, zAh, zAl);

  // a3v = softmax(ql @ k^T) @ v  — flash accumulation + normalize
  // 512 blocks (qt=4 x kt=4), KVBLK=128, T14 async-stage
  k_a3v<<<512, 256, 0, stream>>>(qlh, kb, vb, a3vf, rs3);
  k_a3vnorm<<<512, 256, 0, stream>>>(a3vf, rs3, a3vh, a3vl);

  // Newton-Schulz pinv: 1 init dispatch + 6 fused strip dispatches.
  // 1024 threads/block (16 waves/CU) for latency hiding.
  k_nsy0<<<256, 1024, 0, stream>>>(A2h, zAh, yh, yl);
  bf16 *zch = zAh, *zcl = zAl, *znh = zBh, *znl = zBl;
  bf16 *yih = yh, *yil = yl, *yoh = y2h, *yol = y2l;
  for (int it = 0; it < 6; ++it) {
    if (it < 3)
      k_ns4<0, 0><<<256, 1024, 0, stream>>>(A2h, A2l, yih, yil, zch, zcl, znh, znl, yoh, yol);
    else if (it == 3)
      k_ns4<0, 1><<<256, 1024, 0, stream>>>(A2h, A2l, yih, yil, zch, zcl, znh, znl, yoh, yol);
    else if (it == 4)
      k_ns4<1, 1><<<256, 1024, 0, stream>>>(A2h, A2l, yih, yil, zch, zcl, znh, znl, yoh, yol);
    else
      k_ns4<1, -1><<<256, 1024, 0, stream>>>(A2h, A2l, yih, yil, zch, zcl, znh, znl, yoh, yol);
    bf16* tmp;
    tmp = zch; zch = znh; znh = tmp;
    tmp = zcl; zcl = znl; znl = tmp;
    tmp = yih; yih = yoh; yoh = tmp;
    tmp = yil; yil = yol; yol = tmp;
  }

  // Wt = (z @ a3v)^T
  p = GP{};
  p.A = zch; p.Al = zcl; p.ldA = 256; p.sA = 65536;
  p.B = a3vh; p.Bl = a3vl; p.ldB = 64; p.sB = 16384; p.K = 256;
  p.C0 = Wt;
  mgemm<64, 64, 2, 0, 1, 1, EWT, 0><<<dim3(1, 4, 32), 256, 0, stream>>>(p);

  // oh = softmax(q @ kl^T) @ W (fused), bf16 out — round-11 verified version
  k_attn1w<<<dim3(64, 1, 32), 256, 0, stream>>>(qb, klh, Wt, oh);

  // += depthwise conv residual
  k_conv2<<<2048, 256, 0, stream>>>(vb, res_k, oh);

  // out = gather(oh bf16) @ w_out + bias, glds-staged (BK=64), XCD-affine
  p = GP{};
  p.A = oh; p.ldA = 64; p.B = wot; p.ldB = 512; p.K = 512;
  p.C0 = d_out; p.bias = b_out;
  ggemm<3, EBIAS, 2><<<512, 256, 0, stream>>>(p);
}